// Round 7
// baseline (126.804 us; speedup 1.0000x reference)
//
#include <hip/hip_runtime.h>
#include <hip/hip_bf16.h>

typedef unsigned int u32;
typedef unsigned short u16;
typedef float f32x2 __attribute__((ext_vector_type(2)));
typedef float f32x4 __attribute__((ext_vector_type(4)));
using bf16x8 = __attribute__((ext_vector_type(8))) short;   // MFMA A/B frag (4 VGPRs)
using f32x4v = __attribute__((ext_vector_type(4))) float;   // MFMA C/D frag

#define DEVINL __device__ __forceinline__

// Problem constants: B=8, C=64, D=128, H=128, W=128
constexpr int SCAN_LDS = 32768;   // [128 pos][256B] bf16, XOR-swizzled, exact fit
constexpr int XS = 132;           // stride for k_final transpose staging
constexpr int LDS_X = 128 * XS * 2;   // 33792

DEVINL float bf2f(u16 u) { union { u32 i; float f; } v; v.i = ((u32)u) << 16; return v.f; }
DEVINL float bf2f_lo(u32 u) { union { u32 i; float f; } v; v.i = u << 16; return v.f; }
DEVINL float bf2f_hi(u32 u) { union { u32 i; float f; } v; v.i = u & 0xffff0000u; return v.f; }
DEVINL u16 f2bf(float f) {
  union { float f; u32 i; } v; v.f = f;
  u32 b = v.i;
  b += 0x7fffu + ((b >> 16) & 1u);   // RNE
  return (u16)(b >> 16);
}
DEVINL u32 pack2(float a, float b) { return (u32)f2bf(a) | ((u32)f2bf(b) << 16); }

// ---------------- P0: A=tanh(A_param), Mrow[dir][c][d] bf16, beff ----------------
__global__ __launch_bounds__(256) void k_pre(
    const float* __restrict__ Wf, const float* __restrict__ Wo,
    const float* __restrict__ bf_, const float* __restrict__ bo,
    const float* __restrict__ A_param,
    float* __restrict__ A_t, float* __restrict__ beff, u16* __restrict__ Mrow) {
  const int wg = blockIdx.x, t = threadIdx.x;
  if (wg < 128) {
    const int idx = wg * 256 + t;          // 0..32767
    const int cout = idx >> 9;             // 0..63
    const int k = idx & 511;               // 0..511 = dir*128 + d
    float s = 0.f;
    for (int d = 0; d < 128; ++d) s = fmaf(Wo[cout * 128 + d], Wf[d * 512 + k], s);
    const int dir = k >> 7, dm = k & 127;
    Mrow[(dir * 64 + cout) * 128 + dm] = f2bf(s);
  } else {
    if (t < 128) A_t[t] = tanhf(A_param[t]);
    if (t < 64) {
      float s = bo[t];
      for (int d = 0; d < 128; ++d) s = fmaf(Wo[t * 128 + d], bf_[d], s);
      beff[t] = s;
    }
  }
}

extern __shared__ char smem[];

// ---------------- K_X: x[b][h][w][d] = Wi @ Fmod + bi (MFMA) ----------------
__global__ __launch_bounds__(256, 3) void k_x(
    const float* __restrict__ F_in, const float* __restrict__ prior,
    const float* __restrict__ Wi, const float* __restrict__ bi,
    const float* __restrict__ alpha_p, u16* __restrict__ x_out) {
  char* buf = smem;            // first 16KB: FT [128 w][128B swz]; then x [128 w][256B swz]

  const int t = threadIdx.x;
  const int lane = t & 63, wv = t >> 6, l15 = lane & 15, kg = lane >> 4;
  const int bid = blockIdx.x, b = bid >> 7, h = bid & 127;

  // ---- Wi B-frags (k=c, n=d) into regs ----
  bf16x8 bWi[8][2];
#pragma unroll
  for (int nt = 0; nt < 8; ++nt)
#pragma unroll
    for (int ks = 0; ks < 2; ++ks) {
      const float* wp = Wi + (nt * 16 + l15) * 64 + ks * 32 + kg * 8;
      const f32x4 a = *(const f32x4*)(wp);
      const f32x4 c = *(const f32x4*)(wp + 4);
      union { bf16x8 v; uint4 u; } cv;
      cv.u.x = pack2(a.x, a.y);  cv.u.y = pack2(a.z, a.w);
      cv.u.z = pack2(c.x, c.y);  cv.u.w = pack2(c.z, c.w);
      bWi[nt][ks] = cv.v;
    }

  // ---- stage Fmod^T (bf16): row w = 64 c (128B), swz byte^((w&7)<<4) ----
  {
    const int w = t & 127, ch = t >> 7;
    const float alpha = alpha_p[0];
    const float pv = prior[(b * 128 + h) * 128 + w];
    const float* Fb = F_in + ((size_t)b * 64 + ch * 32) * 16384 + h * 128 + w;
    const u32 sw = (u32)((w & 7) << 4);
    char* rowp = buf + w * 128;
#pragma unroll
    for (int q = 0; q < 4; ++q) {
      float fv[8];
#pragma unroll
      for (int j = 0; j < 8; ++j) fv[j] = fmaf(alpha, pv, Fb[(q * 8 + j) * 16384]);
      uint4 pk;
      pk.x = pack2(fv[0], fv[1]); pk.y = pack2(fv[2], fv[3]);
      pk.z = pack2(fv[4], fv[5]); pk.w = pack2(fv[6], fv[7]);
      *(uint4*)(rowp + ((u32)(ch * 64 + q * 16) ^ sw)) = pk;
    }
  }
  __syncthreads();

  // ---- read A-frags into regs BEFORE buf is overwritten ----
  bf16x8 aF[2][2];   // [ks][mt]
#pragma unroll
  for (int ks = 0; ks < 2; ++ks)
#pragma unroll
    for (int mt = 0; mt < 2; ++mt) {
      const int row = wv * 32 + mt * 16 + l15;
      aF[ks][mt] = *(const bf16x8*)(buf + row * 128 + ((u32)(ks * 64 + kg * 16) ^ ((u32)((row & 7) << 4))));
    }
  __syncthreads();

  // ---- MFMA, acc init = bias; write x -> buf [w][256B swz] ----
  {
    f32x4v acc[2][8];
#pragma unroll
    for (int mt = 0; mt < 2; ++mt)
#pragma unroll
      for (int nt = 0; nt < 8; ++nt) {
        const float bv = bi[nt * 16 + l15];
        acc[mt][nt] = (f32x4v){ bv, bv, bv, bv };
      }
#pragma unroll
    for (int ks = 0; ks < 2; ++ks)
#pragma unroll
      for (int mt = 0; mt < 2; ++mt)
#pragma unroll
        for (int nt = 0; nt < 8; ++nt)
          acc[mt][nt] = __builtin_amdgcn_mfma_f32_16x16x32_bf16(aF[ks][mt], bWi[nt][ks], acc[mt][nt], 0, 0, 0);

#pragma unroll
    for (int mt = 0; mt < 2; ++mt)
#pragma unroll
      for (int nt = 0; nt < 8; ++nt)
#pragma unroll
        for (int r = 0; r < 4; ++r) {
          const int w = wv * 32 + mt * 16 + kg * 4 + r;
          const int d = nt * 16 + l15;
          *(u16*)(buf + w * 256 + ((u32)(d * 2) ^ ((u32)((w & 7) << 4)))) = f2bf(acc[mt][nt][r]);
        }
  }
  __syncthreads();

  // ---- coalesced LDS -> global x_out [w][d] ----
  {
    u16* xg = x_out + (size_t)(b * 128 + h) * 16384;
#pragma unroll
    for (int j = 0; j < 8; ++j) {
      const int i = t + j * 256;
      const int row = i >> 4, q = i & 15;
      const uint4 v = *(const uint4*)(buf + row * 256 + ((u32)(q * 16) ^ ((u32)((row & 7) << 4))));
      *(uint4*)(xg + row * 128 + q * 8) = v;
    }
  }
}

// In-place scan of a d-pair column (u32 = 2 bf16), 8-deep rolling prefetch, swizzled.
template <bool REV>
DEVINL void scan_pair_sw(char* buf, int dp, float A0, float A1, float B0, float B1) {
  float h0 = 0.f, h1 = 0.f;
  const u32 cb = (u32)(dp * 4);
  u32 nx[8];
#pragma unroll
  for (int j = 0; j < 8; ++j) {
    const int i = REV ? (127 - j) : j;
    nx[j] = *(const u32*)(buf + i * 256 + (cb ^ ((u32)((i & 7) << 4))));
  }
  for (int ib = 0; ib < 128; ib += 8) {
    u32 cur[8];
#pragma unroll
    for (int j = 0; j < 8; ++j) cur[j] = nx[j];
    if (ib + 8 < 128) {
#pragma unroll
      for (int j = 0; j < 8; ++j) {
        const int i = REV ? (127 - (ib + 8 + j)) : (ib + 8 + j);
        nx[j] = *(const u32*)(buf + i * 256 + (cb ^ ((u32)((i & 7) << 4))));
      }
    }
#pragma unroll
    for (int j = 0; j < 8; ++j) {
      const int i = REV ? (127 - (ib + j)) : (ib + j);
      h0 = fmaf(A0, h0, B0 * bf2f_lo(cur[j]));
      h1 = fmaf(A1, h1, B1 * bf2f_hi(cur[j]));
      *(u32*)(buf + i * 256 + (cb ^ ((u32)((i & 7) << 4)))) = pack2(h0, h1);
    }
  }
}

// One combine direction: acc2 += M[dir] @ h (h in swizzled buf as [pos][d]).
DEVINL void combine_pass_sw(const char* buf, const u16* __restrict__ Mrow, int dir,
                            int lane, int wv, f32x4v (&acc2)[4][2]) {
  const int l15 = lane & 15, kg = lane >> 4;
  const u32 sw = (u32)((l15 & 7) << 4);
#pragma unroll
  for (int ks = 0; ks < 4; ++ks) {
    bf16x8 afr[4], bfr[2];
#pragma unroll
    for (int ct = 0; ct < 4; ++ct)
      afr[ct] = *(const bf16x8*)(Mrow + ((size_t)dir * 64 + ct * 16 + l15) * 128 + ks * 32 + kg * 8);
#pragma unroll
    for (int pt = 0; pt < 2; ++pt) {
      const int row = wv * 32 + pt * 16 + l15;
      bfr[pt] = *(const bf16x8*)(buf + row * 256 + ((u32)(ks * 64 + kg * 16) ^ sw));
    }
#pragma unroll
    for (int ct = 0; ct < 4; ++ct)
#pragma unroll
      for (int pt = 0; pt < 2; ++pt)
        acc2[ct][pt] = __builtin_amdgcn_mfma_f32_16x16x32_bf16(afr[ct], bfr[pt], acc2[ct][pt], 0, 0, 0);
  }
}

// Store combine acc into buf as f32 [64 c][512B swz rows].
DEVINL void acc_to_outs_sw(const f32x4v (&acc2)[4][2], int lane, int wv, char* buf) {
  const int l15 = lane & 15, kg = lane >> 4;
#pragma unroll
  for (int ct = 0; ct < 4; ++ct)
#pragma unroll
    for (int pt = 0; pt < 2; ++pt)
#pragma unroll
      for (int r = 0; r < 4; ++r) {
        const int row = ct * 16 + kg * 4 + r;
        const int col = wv * 32 + pt * 16 + l15;
        *(float*)(buf + row * 512 + ((u32)(col * 4) ^ ((u32)(((row >> 2) & 7) << 4)))) = acc2[ct][pt][r];
      }
}

// ---------------- scan+combine kernel body (shared by h and v) ----------------
template <bool VERT>
DEVINL void scan_combine_body(const u16* __restrict__ x_ws, const float* __restrict__ Bp,
                              const float* __restrict__ A_t, const u16* __restrict__ Mrow,
                              u16* __restrict__ outg) {
  char* buf = smem;
  const int t = threadIdx.x;
  const int lane = t & 63, wv = t >> 6;
  const int bid = blockIdx.x, b = bid >> 7, p = bid & 127;   // p = h (horiz) or w (vert)

  // ---- stage x rows -> buf swizzled ----
#pragma unroll
  for (int j = 0; j < 8; ++j) {
    const int i = t + j * 256;
    const int row = i >> 4, q = i & 15;
    const uint4 v = VERT
        ? *(const uint4*)(x_ws + ((size_t)(b * 128 + row) * 128 + p) * 128 + q * 8)
        : *(const uint4*)(x_ws + (size_t)(b * 128 + p) * 16384 + row * 128 + q * 8);
    *(uint4*)(buf + row * 256 + ((u32)(q * 16) ^ ((u32)((row & 7) << 4)))) = v;
  }
  __syncthreads();

  // ---- fwd scan ----
  if (t < 128 && lane < 32) {
    const int dp = wv * 32 + lane;
    const f32x2 a = *(const f32x2*)(A_t + dp * 2);
    const f32x2 bb = *(const f32x2*)(Bp + dp * 2);
    scan_pair_sw<false>(buf, dp, a.x, a.y, bb.x, bb.y);
  }
  __syncthreads();

  f32x4v acc2[4][2];
#pragma unroll
  for (int i = 0; i < 4; ++i)
#pragma unroll
    for (int j = 0; j < 2; ++j) acc2[i][j] = (f32x4v)0.f;
  combine_pass_sw(buf, Mrow, VERT ? 2 : 0, lane, wv, acc2);
  __syncthreads();

  // ---- re-stage x (L3-hot) ----
#pragma unroll
  for (int j = 0; j < 8; ++j) {
    const int i = t + j * 256;
    const int row = i >> 4, q = i & 15;
    const uint4 v = VERT
        ? *(const uint4*)(x_ws + ((size_t)(b * 128 + row) * 128 + p) * 128 + q * 8)
        : *(const uint4*)(x_ws + (size_t)(b * 128 + p) * 16384 + row * 128 + q * 8);
    *(uint4*)(buf + row * 256 + ((u32)(q * 16) ^ ((u32)((row & 7) << 4)))) = v;
  }
  __syncthreads();

  // ---- rev scan ----
  if (t < 128 && lane < 32) {
    const int dp = wv * 32 + lane;
    const f32x2 a = *(const f32x2*)(A_t + dp * 2);
    const f32x2 bb = *(const f32x2*)(Bp + dp * 2);
    scan_pair_sw<true>(buf, dp, a.x, a.y, bb.x, bb.y);
  }
  __syncthreads();

  combine_pass_sw(buf, Mrow, VERT ? 3 : 1, lane, wv, acc2);
  __syncthreads();

  acc_to_outs_sw(acc2, lane, wv, buf);
  __syncthreads();

  // ---- write S[c][pos] bf16 -> outg[b][c][p][pos] ----
  u16* og = outg + (size_t)(b * 64) * 16384 + p * 128;
  for (int i = t; i < 4096; i += 256) {
    const int c = i >> 6, p2 = (i & 63) * 2;
    const f32x2 v = *(const f32x2*)(buf + c * 512 + ((u32)(p2 * 4) ^ ((u32)(((c >> 2) & 7) << 4))));
    *(u32*)(og + (size_t)c * 16384 + p2) = pack2(v.x, v.y);
  }
}

__global__ __launch_bounds__(256, 5) void k_scan_h(
    const u16* __restrict__ x_ws, const float* __restrict__ Bp,
    const float* __restrict__ A_t, const u16* __restrict__ Mrow,
    u16* __restrict__ Sh) {
  scan_combine_body<false>(x_ws, Bp, A_t, Mrow, Sh);
}

__global__ __launch_bounds__(256, 5) void k_scan_v(
    const u16* __restrict__ x_ws, const float* __restrict__ Bp,
    const float* __restrict__ A_t, const u16* __restrict__ Mrow,
    u16* __restrict__ accT) {
  scan_combine_body<true>(x_ws, Bp, A_t, Mrow, accT);
}

// ---------------- F: out = F_mod + gamma*(S_h + S_v^T + beff) ----------------
__global__ __launch_bounds__(256) void k_final(
    const float* __restrict__ F_in, const float* __restrict__ prior,
    const float* __restrict__ alpha_p, const float* __restrict__ gamma_p,
    const float* __restrict__ beff, const u16* __restrict__ accT,
    const u16* __restrict__ Sh, float* __restrict__ out) {
  u16* Xu = (u16*)smem;
  u32* Xw = (u32*)smem;
  const int t = threadIdx.x;
  const int bid = blockIdx.x, b = bid >> 6, c = bid & 63;
  const size_t base = (size_t)bid * 16384;   // (b,c) plane

  for (int i = t; i < 2048; i += 256) {
    const int r = i >> 4, j = i & 15;   // r = w row of accT plane
    const uint4 v = *(const uint4*)(accT + base + r * 128 + j * 8);
    u32* dst = Xw + r * 66 + j * 4;
    dst[0] = v.x; dst[1] = v.y; dst[2] = v.z; dst[3] = v.w;
  }
  __syncthreads();
  const float alpha = alpha_p[0], gamma = gamma_p[0];
  const float be = beff[c];
  for (int i = t; i < 2048; i += 256) {
    const int hh = i >> 4, w8 = (i & 15) * 8;
    float sv[8];
#pragma unroll
    for (int q = 0; q < 8; ++q) sv[q] = bf2f(Xu[(w8 + q) * XS + hh]);
    const size_t off = base + hh * 128 + w8;
    const float* Fp = F_in + off;
    const u16* Sp = Sh + off;
    float* Op = out + off;
    const float* Pp = prior + (b * 128 + hh) * 128 + w8;
    const uint4 sh4 = *(const uint4*)(Sp);
    const u16* sh8 = (const u16*)&sh4;
#pragma unroll
    for (int q = 0; q < 8; ++q) {
      Op[q] = Fp[q] + alpha * Pp[q] + gamma * (bf2f(sh8[q]) + be + sv[q]);
    }
  }
}

extern "C" void kernel_launch(void* const* d_in, const int* in_sizes, int n_in,
                              void* d_out, int out_size, void* d_ws, size_t ws_size,
                              hipStream_t stream) {
  const float* F_in   = (const float*)d_in[0];
  const float* prior  = (const float*)d_in[1];
  const float* Wi     = (const float*)d_in[2];
  const float* bi     = (const float*)d_in[3];
  const float* A_par  = (const float*)d_in[4];
  const float* B_par  = (const float*)d_in[5];
  const float* alpha  = (const float*)d_in[6];
  const float* gamma  = (const float*)d_in[7];
  const float* Wf     = (const float*)d_in[8];
  const float* bf_    = (const float*)d_in[9];
  const float* Wo     = (const float*)d_in[10];
  const float* bo     = (const float*)d_in[11];
  float* out = (float*)d_out;

  char* ws = (char*)d_ws;
  float* A_t   = (float*)ws;                       // 512 B
  float* beff  = (float*)(ws + 512);               // 256 B
  u16*   Mrow  = (u16*)(ws + 1024);                // 64 KB: [4][64][128] bf16
  u16*   x_ws  = (u16*)(ws + 66560);               // 33.5 MB: x[b][h][w][d] bf16
  u16*   Sh_ws = (u16*)(ws + 66560 + 33554432);    // 16.8 MB: [b][c][h][w] bf16
  u16*   accT  = (u16*)(ws + 66560 + 50331648);    // 16.8 MB: [b][c][w][h] bf16

  hipFuncSetAttribute((const void*)k_x,      hipFuncAttributeMaxDynamicSharedMemorySize, SCAN_LDS);
  hipFuncSetAttribute((const void*)k_scan_h, hipFuncAttributeMaxDynamicSharedMemorySize, SCAN_LDS);
  hipFuncSetAttribute((const void*)k_scan_v, hipFuncAttributeMaxDynamicSharedMemorySize, SCAN_LDS);

  k_pre   <<<129, 256, 0, stream>>>(Wf, Wo, bf_, bo, A_par, A_t, beff, Mrow);
  k_x     <<<1024, 256, SCAN_LDS, stream>>>(F_in, prior, Wi, bi, alpha, x_ws);
  k_scan_h<<<1024, 256, SCAN_LDS, stream>>>(x_ws, B_par, A_t, Mrow, Sh_ws);
  k_scan_v<<<1024, 256, SCAN_LDS, stream>>>(x_ws, B_par, A_t, Mrow, accT);
  k_final <<<512, 256, LDS_X, stream>>>(F_in, prior, alpha, gamma, beff, accT, Sh_ws, out);
}

// Round 8
// 120.562 us; speedup vs baseline: 1.0518x; 1.0518x over previous
//
#include <hip/hip_runtime.h>
#include <hip/hip_bf16.h>

typedef unsigned int u32;
typedef unsigned short u16;
typedef float f32x2 __attribute__((ext_vector_type(2)));
typedef float f32x4 __attribute__((ext_vector_type(4)));
using bf16x8 = __attribute__((ext_vector_type(8))) short;   // MFMA A/B frag (4 VGPRs)
using f32x4v = __attribute__((ext_vector_type(4))) float;   // MFMA C/D frag

#define DEVINL __device__ __forceinline__

// Problem constants: B=8, C=64, D=128, H=128, W=128
constexpr int SCAN_LDS = 32768;   // [128 pos][256B] bf16, XOR-swizzled
constexpr int XS = 132;           // stride for k_final transpose staging
constexpr int LDS_X = 128 * XS * 2;   // 33792

DEVINL float bf2f(u16 u) { union { u32 i; float f; } v; v.i = ((u32)u) << 16; return v.f; }
DEVINL float bf2f_lo(u32 u) { union { u32 i; float f; } v; v.i = u << 16; return v.f; }
DEVINL float bf2f_hi(u32 u) { union { u32 i; float f; } v; v.i = u & 0xffff0000u; return v.f; }
DEVINL u16 f2bf(float f) {
  union { float f; u32 i; } v; v.f = f;
  u32 b = v.i;
  b += 0x7fffu + ((b >> 16) & 1u);   // RNE
  return (u16)(b >> 16);
}
DEVINL u32 pack2(float a, float b) { return (u32)f2bf(a) | ((u32)f2bf(b) << 16); }

// ---------------- P0: A=tanh(A_param), Mrow[dir][c][d] bf16, beff ----------------
__global__ __launch_bounds__(256) void k_pre(
    const float* __restrict__ Wf, const float* __restrict__ Wo,
    const float* __restrict__ bf_, const float* __restrict__ bo,
    const float* __restrict__ A_param,
    float* __restrict__ A_t, float* __restrict__ beff, u16* __restrict__ Mrow) {
  const int wg = blockIdx.x, t = threadIdx.x;
  if (wg < 128) {
    const int idx = wg * 256 + t;          // 0..32767
    const int cout = idx >> 9;             // 0..63
    const int k = idx & 511;               // 0..511 = dir*128 + d
    float s = 0.f;
    for (int d = 0; d < 128; ++d) s = fmaf(Wo[cout * 128 + d], Wf[d * 512 + k], s);
    const int dir = k >> 7, dm = k & 127;
    Mrow[(dir * 64 + cout) * 128 + dm] = f2bf(s);
  } else {
    if (t < 128) A_t[t] = tanhf(A_param[t]);
    if (t < 64) {
      float s = bo[t];
      for (int d = 0; d < 128; ++d) s = fmaf(Wo[t * 128 + d], bf_[d], s);
      beff[t] = s;
    }
  }
}

extern __shared__ char smem[];

// In-place scan of a d-pair column (u32 = 2 bf16), 8-deep rolling prefetch, swizzled.
template <bool REV>
DEVINL void scan_pair_sw(char* buf, int dp, float A0, float A1, float B0, float B1) {
  float h0 = 0.f, h1 = 0.f;
  const u32 cb = (u32)(dp * 4);
  u32 nx[8];
#pragma unroll
  for (int j = 0; j < 8; ++j) {
    const int i = REV ? (127 - j) : j;
    nx[j] = *(const u32*)(buf + i * 256 + (cb ^ ((u32)((i & 7) << 4))));
  }
  for (int ib = 0; ib < 128; ib += 8) {
    u32 cur[8];
#pragma unroll
    for (int j = 0; j < 8; ++j) cur[j] = nx[j];
    if (ib + 8 < 128) {
#pragma unroll
      for (int j = 0; j < 8; ++j) {
        const int i = REV ? (127 - (ib + 8 + j)) : (ib + 8 + j);
        nx[j] = *(const u32*)(buf + i * 256 + (cb ^ ((u32)((i & 7) << 4))));
      }
    }
#pragma unroll
    for (int j = 0; j < 8; ++j) {
      const int i = REV ? (127 - (ib + j)) : (ib + j);
      h0 = fmaf(A0, h0, B0 * bf2f_lo(cur[j]));
      h1 = fmaf(A1, h1, B1 * bf2f_hi(cur[j]));
      *(u32*)(buf + i * 256 + (cb ^ ((u32)((i & 7) << 4)))) = pack2(h0, h1);
    }
  }
}

// One combine direction: acc2 += M[dir] @ h (h in swizzled buf as [pos][d]).
DEVINL void combine_pass_sw(const char* buf, const u16* __restrict__ Mrow, int dir,
                            int lane, int wv, f32x4v (&acc2)[4][2]) {
  const int l15 = lane & 15, kg = lane >> 4;
  const u32 sw = (u32)((l15 & 7) << 4);
#pragma unroll
  for (int ks = 0; ks < 4; ++ks) {
    bf16x8 afr[4], bfr[2];
#pragma unroll
    for (int ct = 0; ct < 4; ++ct)
      afr[ct] = *(const bf16x8*)(Mrow + ((size_t)dir * 64 + ct * 16 + l15) * 128 + ks * 32 + kg * 8);
#pragma unroll
    for (int pt = 0; pt < 2; ++pt) {
      const int row = wv * 32 + pt * 16 + l15;
      bfr[pt] = *(const bf16x8*)(buf + row * 256 + ((u32)(ks * 64 + kg * 16) ^ sw));
    }
#pragma unroll
    for (int ct = 0; ct < 4; ++ct)
#pragma unroll
      for (int pt = 0; pt < 2; ++pt)
        acc2[ct][pt] = __builtin_amdgcn_mfma_f32_16x16x32_bf16(afr[ct], bfr[pt], acc2[ct][pt], 0, 0, 0);
  }
}

// Store combine acc into buf as f32 [64 c][512B swz rows].
DEVINL void acc_to_outs_sw(const f32x4v (&acc2)[4][2], int lane, int wv, char* buf) {
  const int l15 = lane & 15, kg = lane >> 4;
#pragma unroll
  for (int ct = 0; ct < 4; ++ct)
#pragma unroll
    for (int pt = 0; pt < 2; ++pt)
#pragma unroll
      for (int r = 0; r < 4; ++r) {
        const int row = ct * 16 + kg * 4 + r;
        const int col = wv * 32 + pt * 16 + l15;
        *(float*)(buf + row * 512 + ((u32)(col * 4) ^ ((u32)(((row >> 2) & 7) << 4)))) = acc2[ct][pt][r];
      }
}

// ---------------- K_A: x-GEMM + horizontal scans + combine ----------------
// Writes x_t[b][w][h][d] (transposed for k_B) and Sh[b][c][h][w] bf16.
__global__ __launch_bounds__(256, 4) void k_A(
    const float* __restrict__ F_in, const float* __restrict__ prior,
    const float* __restrict__ Wi, const float* __restrict__ bi,
    const float* __restrict__ Bp, const float* __restrict__ alpha_p,
    const float* __restrict__ A_t, const u16* __restrict__ Mrow,
    u16* __restrict__ x_t, u16* __restrict__ Sh) {
  char* buf = smem;   // 32 KB: FT (16 KB) -> x [128 w][256B swz] -> OutS

  const int t = threadIdx.x;
  const int lane = t & 63, wv = t >> 6, l15 = lane & 15, kg = lane >> 4;
  const int bid = blockIdx.x, b = bid >> 7, h = bid & 127;

  // ---- P1: stage Fmod^T (bf16): row w = 64 c (128B), swz byte^((w&7)<<4) ----
  {
    const int w = t & 127, ch = t >> 7;
    const float alpha = alpha_p[0];
    const float pv = prior[(b * 128 + h) * 128 + w];
    const float* Fb = F_in + ((size_t)b * 64 + ch * 32) * 16384 + h * 128 + w;
    const u32 sw = (u32)((w & 7) << 4);
    char* rowp = buf + w * 128;
#pragma unroll
    for (int q = 0; q < 4; ++q) {
      float fv[8];
#pragma unroll
      for (int j = 0; j < 8; ++j) fv[j] = fmaf(alpha, pv, Fb[(q * 8 + j) * 16384]);
      uint4 pk;
      pk.x = pack2(fv[0], fv[1]); pk.y = pack2(fv[2], fv[3]);
      pk.z = pack2(fv[4], fv[5]); pk.w = pack2(fv[6], fv[7]);
      *(uint4*)(rowp + ((u32)(ch * 64 + q * 16) ^ sw)) = pk;
    }
  }
  __syncthreads();

  // ---- P2: read A-frags into regs ----
  bf16x8 aF[2][2];   // [ks][mt]
#pragma unroll
  for (int ks = 0; ks < 2; ++ks)
#pragma unroll
    for (int mt = 0; mt < 2; ++mt) {
      const int row = wv * 32 + mt * 16 + l15;
      aF[ks][mt] = *(const bf16x8*)(buf + row * 128 + ((u32)(ks * 64 + kg * 16) ^ ((u32)((row & 7) << 4))));
    }
  __syncthreads();

  // ---- P3: GEMM with on-demand Wi frags; write x -> buf [w][256B swz] ----
  {
    f32x4v acc[2][8];
#pragma unroll
    for (int mt = 0; mt < 2; ++mt)
#pragma unroll
      for (int nt = 0; nt < 8; ++nt) {
        const float bv = bi[nt * 16 + l15];
        acc[mt][nt] = (f32x4v){ bv, bv, bv, bv };
      }
#pragma unroll
    for (int ks = 0; ks < 2; ++ks)
#pragma unroll
      for (int nt = 0; nt < 8; ++nt) {
        const float* wp = Wi + (nt * 16 + l15) * 64 + ks * 32 + kg * 8;
        const f32x4 a = *(const f32x4*)(wp);
        const f32x4 c = *(const f32x4*)(wp + 4);
        union { bf16x8 v; uint4 u; } cv;
        cv.u.x = pack2(a.x, a.y);  cv.u.y = pack2(a.z, a.w);
        cv.u.z = pack2(c.x, c.y);  cv.u.w = pack2(c.z, c.w);
        acc[0][nt] = __builtin_amdgcn_mfma_f32_16x16x32_bf16(aF[ks][0], cv.v, acc[0][nt], 0, 0, 0);
        acc[1][nt] = __builtin_amdgcn_mfma_f32_16x16x32_bf16(aF[ks][1], cv.v, acc[1][nt], 0, 0, 0);
      }
#pragma unroll
    for (int mt = 0; mt < 2; ++mt)
#pragma unroll
      for (int nt = 0; nt < 8; ++nt)
#pragma unroll
        for (int r = 0; r < 4; ++r) {
          const int w = wv * 32 + mt * 16 + kg * 4 + r;
          const int d = nt * 16 + l15;
          *(u16*)(buf + w * 256 + ((u32)(d * 2) ^ ((u32)((w & 7) << 4)))) = f2bf(acc[mt][nt][r]);
        }
  }
  __syncthreads();

  // ---- P4: rld stash + x_t[b][w][h][d] global write (256B rows) ----
  uint4 rld[8];
#pragma unroll
  for (int j = 0; j < 8; ++j) {
    const int i = t + j * 256;
    const int row = i >> 4, q = i & 15;
    rld[j] = *(const uint4*)(buf + row * 256 + ((u32)(q * 16) ^ ((u32)((row & 7) << 4))));
    *(uint4*)(x_t + ((size_t)(b * 128 + row) * 128 + h) * 128 + q * 8) = rld[j];
  }
  __syncthreads();

  // ---- P5: fwd scan (lr) ----
  if (t < 128 && lane < 32) {
    const int dp = wv * 32 + lane;
    const f32x2 a = *(const f32x2*)(A_t + dp * 2);
    const f32x2 bb = *(const f32x2*)(Bp + dp * 2);
    scan_pair_sw<false>(buf, dp, a.x, a.y, bb.x, bb.y);
  }
  __syncthreads();

  // ---- P6: combine dir 0 ----
  f32x4v acc2[4][2];
#pragma unroll
  for (int i = 0; i < 4; ++i)
#pragma unroll
    for (int j = 0; j < 2; ++j) acc2[i][j] = (f32x4v)0.f;
  combine_pass_sw(buf, Mrow, 0, lane, wv, acc2);
  __syncthreads();

  // ---- P7: restore x from rld ----
#pragma unroll
  for (int j = 0; j < 8; ++j) {
    const int i = t + j * 256;
    const int row = i >> 4, q = i & 15;
    *(uint4*)(buf + row * 256 + ((u32)(q * 16) ^ ((u32)((row & 7) << 4)))) = rld[j];
  }
  __syncthreads();

  // ---- P8: rev scan (rl) ----
  if (t < 128 && lane < 32) {
    const int dp = wv * 32 + lane;
    const f32x2 a = *(const f32x2*)(A_t + dp * 2);
    const f32x2 bb = *(const f32x2*)(Bp + dp * 2);
    scan_pair_sw<true>(buf, dp, a.x, a.y, bb.x, bb.y);
  }
  __syncthreads();

  // ---- P9: combine dir 1 ----
  combine_pass_sw(buf, Mrow, 1, lane, wv, acc2);
  __syncthreads();

  // ---- P10: acc -> OutS in buf ----
  acc_to_outs_sw(acc2, lane, wv, buf);
  __syncthreads();

  // ---- P11: Sh[b][c][h][w] bf16 ----
  u16* og = Sh + (size_t)(b * 64) * 16384 + h * 128;
  for (int i = t; i < 4096; i += 256) {
    const int c = i >> 6, p2 = (i & 63) * 2;
    const f32x2 v = *(const f32x2*)(buf + c * 512 + ((u32)(p2 * 4) ^ ((u32)(((c >> 2) & 7) << 4))));
    *(u32*)(og + (size_t)c * 16384 + p2) = pack2(v.x, v.y);
  }
}

// ---------------- K_B: vertical scans + combine -> accT[b,c,w,h] ----------------
__global__ __launch_bounds__(256, 4) void k_B(
    const u16* __restrict__ x_t, const float* __restrict__ Bp,
    const float* __restrict__ A_t, const u16* __restrict__ Mrow,
    u16* __restrict__ accT) {
  char* buf = smem;
  const int t = threadIdx.x;
  const int lane = t & 63, wv = t >> 6;
  const int bid = blockIdx.x, b = bid >> 7, w = bid & 127;

  // ---- stage x_t plane (b,w): fully contiguous 32 KB ----
  uint4 rld[8];
#pragma unroll
  for (int j = 0; j < 8; ++j) {
    const int i = t + j * 256;
    const int row = i >> 4, q = i & 15;
    rld[j] = *(const uint4*)(x_t + ((size_t)(b * 128 + w) * 128 + row) * 128 + q * 8);
  }
#pragma unroll
  for (int j = 0; j < 8; ++j) {
    const int i = t + j * 256;
    const int row = i >> 4, q = i & 15;
    *(uint4*)(buf + row * 256 + ((u32)(q * 16) ^ ((u32)((row & 7) << 4)))) = rld[j];
  }
  __syncthreads();

  // ---- fwd scan (tb) ----
  if (t < 128 && lane < 32) {
    const int dp = wv * 32 + lane;
    const f32x2 a = *(const f32x2*)(A_t + dp * 2);
    const f32x2 bb = *(const f32x2*)(Bp + dp * 2);
    scan_pair_sw<false>(buf, dp, a.x, a.y, bb.x, bb.y);
  }
  __syncthreads();

  f32x4v acc2[4][2];
#pragma unroll
  for (int i = 0; i < 4; ++i)
#pragma unroll
    for (int j = 0; j < 2; ++j) acc2[i][j] = (f32x4v)0.f;
  combine_pass_sw(buf, Mrow, 2, lane, wv, acc2);
  __syncthreads();

  // ---- restore x from rld ----
#pragma unroll
  for (int j = 0; j < 8; ++j) {
    const int i = t + j * 256;
    const int row = i >> 4, q = i & 15;
    *(uint4*)(buf + row * 256 + ((u32)(q * 16) ^ ((u32)((row & 7) << 4)))) = rld[j];
  }
  __syncthreads();

  // ---- rev scan (bt) ----
  if (t < 128 && lane < 32) {
    const int dp = wv * 32 + lane;
    const f32x2 a = *(const f32x2*)(A_t + dp * 2);
    const f32x2 bb = *(const f32x2*)(Bp + dp * 2);
    scan_pair_sw<true>(buf, dp, a.x, a.y, bb.x, bb.y);
  }
  __syncthreads();

  combine_pass_sw(buf, Mrow, 3, lane, wv, acc2);
  __syncthreads();

  acc_to_outs_sw(acc2, lane, wv, buf);
  __syncthreads();

  // ---- accT[b][c][w][h] bf16 ----
  for (int i = t; i < 4096; i += 256) {
    const int c = i >> 6, h2 = (i & 63) * 2;
    const f32x2 v = *(const f32x2*)(buf + c * 512 + ((u32)(h2 * 4) ^ ((u32)(((c >> 2) & 7) << 4))));
    *(u32*)(accT + ((size_t)(b * 64 + c) * 128 + w) * 128 + h2) = pack2(v.x, v.y);
  }
}

// ---------------- F: out = F_mod + gamma*(S_h + S_v^T + beff) ----------------
__global__ __launch_bounds__(256) void k_final(
    const float* __restrict__ F_in, const float* __restrict__ prior,
    const float* __restrict__ alpha_p, const float* __restrict__ gamma_p,
    const float* __restrict__ beff, const u16* __restrict__ accT,
    const u16* __restrict__ Sh, float* __restrict__ out) {
  u16* Xu = (u16*)smem;
  u32* Xw = (u32*)smem;
  const int t = threadIdx.x;
  const int bid = blockIdx.x, b = bid >> 6, c = bid & 63;
  const size_t base = (size_t)bid * 16384;   // (b,c) plane

  for (int i = t; i < 2048; i += 256) {
    const int r = i >> 4, j = i & 15;   // r = w row of accT plane
    const uint4 v = *(const uint4*)(accT + base + r * 128 + j * 8);
    u32* dst = Xw + r * 66 + j * 4;
    dst[0] = v.x; dst[1] = v.y; dst[2] = v.z; dst[3] = v.w;
  }
  __syncthreads();
  const float alpha = alpha_p[0], gamma = gamma_p[0];
  const float be = beff[c];
  for (int i = t; i < 2048; i += 256) {
    const int hh = i >> 4, w8 = (i & 15) * 8;
    float sv[8];
#pragma unroll
    for (int q = 0; q < 8; ++q) sv[q] = bf2f(Xu[(w8 + q) * XS + hh]);
    const size_t off = base + hh * 128 + w8;
    const float* Fp = F_in + off;
    const u16* Sp = Sh + off;
    float* Op = out + off;
    const float* Pp = prior + (b * 128 + hh) * 128 + w8;
    const uint4 sh4 = *(const uint4*)(Sp);
    const u16* sh8 = (const u16*)&sh4;
#pragma unroll
    for (int q = 0; q < 8; ++q) {
      Op[q] = Fp[q] + alpha * Pp[q] + gamma * (bf2f(sh8[q]) + be + sv[q]);
    }
  }
}

extern "C" void kernel_launch(void* const* d_in, const int* in_sizes, int n_in,
                              void* d_out, int out_size, void* d_ws, size_t ws_size,
                              hipStream_t stream) {
  const float* F_in   = (const float*)d_in[0];
  const float* prior  = (const float*)d_in[1];
  const float* Wi     = (const float*)d_in[2];
  const float* bi     = (const float*)d_in[3];
  const float* A_par  = (const float*)d_in[4];
  const float* B_par  = (const float*)d_in[5];
  const float* alpha  = (const float*)d_in[6];
  const float* gamma  = (const float*)d_in[7];
  const float* Wf     = (const float*)d_in[8];
  const float* bf_    = (const float*)d_in[9];
  const float* Wo     = (const float*)d_in[10];
  const float* bo     = (const float*)d_in[11];
  float* out = (float*)d_out;

  char* ws = (char*)d_ws;
  float* A_t   = (float*)ws;                       // 512 B
  float* beff  = (float*)(ws + 512);               // 256 B
  u16*   Mrow  = (u16*)(ws + 1024);                // 64 KB: [4][64][128] bf16
  u16*   x_t   = (u16*)(ws + 66560);               // 33.5 MB: x[b][w][h][d] bf16
  u16*   Sh_ws = (u16*)(ws + 66560 + 33554432);    // 16.8 MB: [b][c][h][w] bf16
  u16*   accT  = (u16*)(ws + 66560 + 50331648);    // 16.8 MB: [b][c][w][h] bf16

  hipFuncSetAttribute((const void*)k_A, hipFuncAttributeMaxDynamicSharedMemorySize, SCAN_LDS);
  hipFuncSetAttribute((const void*)k_B, hipFuncAttributeMaxDynamicSharedMemorySize, SCAN_LDS);

  k_pre  <<<129, 256, 0, stream>>>(Wf, Wo, bf_, bo, A_par, A_t, beff, Mrow);
  k_A    <<<1024, 256, SCAN_LDS, stream>>>(F_in, prior, Wi, bi, B_par, alpha, A_t, Mrow, x_t, Sh_ws);
  k_B    <<<1024, 256, SCAN_LDS, stream>>>(x_t, B_par, A_t, Mrow, accT);
  k_final<<<512, 256, LDS_X, stream>>>(F_in, prior, alpha, gamma, beff, accT, Sh_ws, out);
}

// Round 9
// 113.665 us; speedup vs baseline: 1.1156x; 1.0607x over previous
//
#include <hip/hip_runtime.h>
#include <hip/hip_bf16.h>

typedef unsigned int u32;
typedef unsigned short u16;
typedef float f32x2 __attribute__((ext_vector_type(2)));
typedef float f32x4 __attribute__((ext_vector_type(4)));
using bf16x8 = __attribute__((ext_vector_type(8))) short;   // MFMA A/B frag (4 VGPRs)
using f32x4v = __attribute__((ext_vector_type(4))) float;   // MFMA C/D frag

#define DEVINL __device__ __forceinline__

// Problem constants: B=8, C=64, D=128, H=128, W=128
constexpr int SCAN_LDS = 32768;   // [128 pos][256B] bf16, XOR-swizzled
constexpr int XS = 132;           // stride for k_final transpose staging
constexpr int LDS_X = 128 * XS * 2;   // 33792

DEVINL float bf2f(u16 u) { union { u32 i; float f; } v; v.i = ((u32)u) << 16; return v.f; }
DEVINL float bf2f_lo(u32 u) { union { u32 i; float f; } v; v.i = u << 16; return v.f; }
DEVINL float bf2f_hi(u32 u) { union { u32 i; float f; } v; v.i = u & 0xffff0000u; return v.f; }
DEVINL u16 f2bf(float f) {
  union { float f; u32 i; } v; v.f = f;
  u32 b = v.i;
  b += 0x7fffu + ((b >> 16) & 1u);   // RNE
  return (u16)(b >> 16);
}
DEVINL u32 pack2(float a, float b) { return (u32)f2bf(a) | ((u32)f2bf(b) << 16); }

// ---------------- P0: A=tanh(A_param), Mrow[dir][c][d] bf16, beff ----------------
__global__ __launch_bounds__(256) void k_pre(
    const float* __restrict__ Wf, const float* __restrict__ Wo,
    const float* __restrict__ bf_, const float* __restrict__ bo,
    const float* __restrict__ A_param,
    float* __restrict__ A_t, float* __restrict__ beff, u16* __restrict__ Mrow) {
  const int wg = blockIdx.x, t = threadIdx.x;
  if (wg < 128) {
    const int idx = wg * 256 + t;          // 0..32767
    const int cout = idx >> 9;             // 0..63
    const int k = idx & 511;               // 0..511 = dir*128 + d
    float s = 0.f;
    for (int d = 0; d < 128; ++d) s = fmaf(Wo[cout * 128 + d], Wf[d * 512 + k], s);
    const int dir = k >> 7, dm = k & 127;
    Mrow[(dir * 64 + cout) * 128 + dm] = f2bf(s);
  } else {
    if (t < 128) A_t[t] = tanhf(A_param[t]);
    if (t < 64) {
      float s = bo[t];
      for (int d = 0; d < 128; ++d) s = fmaf(Wo[t * 128 + d], bf_[d], s);
      beff[t] = s;
    }
  }
}

extern __shared__ char smem[];

// In-place scan of a d-pair column (u32 = 2 bf16), 8-deep rolling prefetch, swizzled.
template <bool REV>
DEVINL void scan_pair_sw(char* buf, int dp, float A0, float A1, float B0, float B1) {
  float h0 = 0.f, h1 = 0.f;
  const u32 cb = (u32)(dp * 4);
  u32 nx[8];
#pragma unroll
  for (int j = 0; j < 8; ++j) {
    const int i = REV ? (127 - j) : j;
    nx[j] = *(const u32*)(buf + i * 256 + (cb ^ ((u32)((i & 7) << 4))));
  }
  for (int ib = 0; ib < 128; ib += 8) {
    u32 cur[8];
#pragma unroll
    for (int j = 0; j < 8; ++j) cur[j] = nx[j];
    if (ib + 8 < 128) {
#pragma unroll
      for (int j = 0; j < 8; ++j) {
        const int i = REV ? (127 - (ib + 8 + j)) : (ib + 8 + j);
        nx[j] = *(const u32*)(buf + i * 256 + (cb ^ ((u32)((i & 7) << 4))));
      }
    }
#pragma unroll
    for (int j = 0; j < 8; ++j) {
      const int i = REV ? (127 - (ib + j)) : (ib + j);
      h0 = fmaf(A0, h0, B0 * bf2f_lo(cur[j]));
      h1 = fmaf(A1, h1, B1 * bf2f_hi(cur[j]));
      *(u32*)(buf + i * 256 + (cb ^ ((u32)((i & 7) << 4)))) = pack2(h0, h1);
    }
  }
}

// One combine direction: acc2 += M[dir] @ h (h in swizzled buf as [pos][d]).
DEVINL void combine_pass_sw(const char* buf, const u16* __restrict__ Mrow, int dir,
                            int lane, int wv, f32x4v (&acc2)[4][2]) {
  const int l15 = lane & 15, kg = lane >> 4;
  const u32 sw = (u32)((l15 & 7) << 4);
#pragma unroll
  for (int ks = 0; ks < 4; ++ks) {
    bf16x8 afr[4], bfr[2];
#pragma unroll
    for (int ct = 0; ct < 4; ++ct)
      afr[ct] = *(const bf16x8*)(Mrow + ((size_t)dir * 64 + ct * 16 + l15) * 128 + ks * 32 + kg * 8);
#pragma unroll
    for (int pt = 0; pt < 2; ++pt) {
      const int row = wv * 32 + pt * 16 + l15;
      bfr[pt] = *(const bf16x8*)(buf + row * 256 + ((u32)(ks * 64 + kg * 16) ^ sw));
    }
#pragma unroll
    for (int ct = 0; ct < 4; ++ct)
#pragma unroll
      for (int pt = 0; pt < 2; ++pt)
        acc2[ct][pt] = __builtin_amdgcn_mfma_f32_16x16x32_bf16(afr[ct], bfr[pt], acc2[ct][pt], 0, 0, 0);
  }
}

// Store combine acc into buf as f32 [64 c][512B swz rows].
DEVINL void acc_to_outs_sw(const f32x4v (&acc2)[4][2], int lane, int wv, char* buf) {
  const int l15 = lane & 15, kg = lane >> 4;
#pragma unroll
  for (int ct = 0; ct < 4; ++ct)
#pragma unroll
    for (int pt = 0; pt < 2; ++pt)
#pragma unroll
      for (int r = 0; r < 4; ++r) {
        const int row = ct * 16 + kg * 4 + r;
        const int col = wv * 32 + pt * 16 + l15;
        *(float*)(buf + row * 512 + ((u32)(col * 4) ^ ((u32)(((row >> 2) & 7) << 4)))) = acc2[ct][pt][r];
      }
}

// ---------------- K_A: x-GEMM + horizontal scans + combine ----------------
// Writes x_ws[b][h][w][d] (contiguous 32 KB/block) and Sh2[b][h][c][w] (contiguous 16 KB/block).
__global__ __launch_bounds__(256, 4) void k_A(
    const float* __restrict__ F_in, const float* __restrict__ prior,
    const float* __restrict__ Wi, const float* __restrict__ bi,
    const float* __restrict__ Bp, const float* __restrict__ alpha_p,
    const float* __restrict__ A_t, const u16* __restrict__ Mrow,
    u16* __restrict__ x_ws, u16* __restrict__ Sh2) {
  char* buf = smem;   // 32 KB: FT (16 KB) -> x [128 w][256B swz] -> OutS

  const int t = threadIdx.x;
  const int lane = t & 63, wv = t >> 6, l15 = lane & 15, kg = lane >> 4;
  const int bid = blockIdx.x, b = bid >> 7, h = bid & 127;
  u16* xg = x_ws + (size_t)(b * 128 + h) * 16384;   // this block's x plane [w][d]

  // ---- P1: stage Fmod^T (bf16): row w = 64 c (128B), swz byte^((w&7)<<4) ----
  {
    const int w = t & 127, ch = t >> 7;
    const float alpha = alpha_p[0];
    const float pv = prior[(b * 128 + h) * 128 + w];
    const float* Fb = F_in + ((size_t)b * 64 + ch * 32) * 16384 + h * 128 + w;
    const u32 sw = (u32)((w & 7) << 4);
    char* rowp = buf + w * 128;
#pragma unroll
    for (int q = 0; q < 4; ++q) {
      float fv[8];
#pragma unroll
      for (int j = 0; j < 8; ++j) fv[j] = fmaf(alpha, pv, Fb[(q * 8 + j) * 16384]);
      uint4 pk;
      pk.x = pack2(fv[0], fv[1]); pk.y = pack2(fv[2], fv[3]);
      pk.z = pack2(fv[4], fv[5]); pk.w = pack2(fv[6], fv[7]);
      *(uint4*)(rowp + ((u32)(ch * 64 + q * 16) ^ sw)) = pk;
    }
  }
  __syncthreads();

  // ---- P2: read A-frags into regs ----
  bf16x8 aF[2][2];   // [ks][mt]
#pragma unroll
  for (int ks = 0; ks < 2; ++ks)
#pragma unroll
    for (int mt = 0; mt < 2; ++mt) {
      const int row = wv * 32 + mt * 16 + l15;
      aF[ks][mt] = *(const bf16x8*)(buf + row * 128 + ((u32)(ks * 64 + kg * 16) ^ ((u32)((row & 7) << 4))));
    }
  __syncthreads();

  // ---- P3: GEMM with on-demand Wi frags; write x -> buf [w][256B swz] ----
  {
    f32x4v acc[2][8];
#pragma unroll
    for (int mt = 0; mt < 2; ++mt)
#pragma unroll
      for (int nt = 0; nt < 8; ++nt) {
        const float bv = bi[nt * 16 + l15];
        acc[mt][nt] = (f32x4v){ bv, bv, bv, bv };
      }
#pragma unroll
    for (int ks = 0; ks < 2; ++ks)
#pragma unroll
      for (int nt = 0; nt < 8; ++nt) {
        const float* wp = Wi + (nt * 16 + l15) * 64 + ks * 32 + kg * 8;
        const f32x4 a = *(const f32x4*)(wp);
        const f32x4 c = *(const f32x4*)(wp + 4);
        union { bf16x8 v; uint4 u; } cv;
        cv.u.x = pack2(a.x, a.y);  cv.u.y = pack2(a.z, a.w);
        cv.u.z = pack2(c.x, c.y);  cv.u.w = pack2(c.z, c.w);
        acc[0][nt] = __builtin_amdgcn_mfma_f32_16x16x32_bf16(aF[ks][0], cv.v, acc[0][nt], 0, 0, 0);
        acc[1][nt] = __builtin_amdgcn_mfma_f32_16x16x32_bf16(aF[ks][1], cv.v, acc[1][nt], 0, 0, 0);
      }
#pragma unroll
    for (int mt = 0; mt < 2; ++mt)
#pragma unroll
      for (int nt = 0; nt < 8; ++nt)
#pragma unroll
        for (int r = 0; r < 4; ++r) {
          const int w = wv * 32 + mt * 16 + kg * 4 + r;
          const int d = nt * 16 + l15;
          *(u16*)(buf + w * 256 + ((u32)(d * 2) ^ ((u32)((w & 7) << 4)))) = f2bf(acc[mt][nt][r]);
        }
  }
  __syncthreads();

  // ---- P4: x -> global (CONTIGUOUS 32 KB stream; no reg stash) ----
#pragma unroll
  for (int j = 0; j < 8; ++j) {
    const int i = t + j * 256;
    const int row = i >> 4, q = i & 15;
    const uint4 v = *(const uint4*)(buf + row * 256 + ((u32)(q * 16) ^ ((u32)((row & 7) << 4))));
    *(uint4*)(xg + row * 128 + q * 8) = v;
  }
  __syncthreads();

  // ---- P5: fwd scan (lr) ----
  if (t < 128 && lane < 32) {
    const int dp = wv * 32 + lane;
    const f32x2 a = *(const f32x2*)(A_t + dp * 2);
    const f32x2 bb = *(const f32x2*)(Bp + dp * 2);
    scan_pair_sw<false>(buf, dp, a.x, a.y, bb.x, bb.y);
  }
  __syncthreads();

  // ---- P6: combine dir 0 ----
  f32x4v acc2[4][2];
#pragma unroll
  for (int i = 0; i < 4; ++i)
#pragma unroll
    for (int j = 0; j < 2; ++j) acc2[i][j] = (f32x4v)0.f;
  combine_pass_sw(buf, Mrow, 0, lane, wv, acc2);
  __syncthreads();

  // ---- P7: restore x by re-reading own plane (L2-hit; syncthreads drained vmcnt) ----
#pragma unroll
  for (int j = 0; j < 8; ++j) {
    const int i = t + j * 256;
    const int row = i >> 4, q = i & 15;
    const uint4 v = *(const uint4*)(xg + row * 128 + q * 8);
    *(uint4*)(buf + row * 256 + ((u32)(q * 16) ^ ((u32)((row & 7) << 4)))) = v;
  }
  __syncthreads();

  // ---- P8: rev scan (rl) ----
  if (t < 128 && lane < 32) {
    const int dp = wv * 32 + lane;
    const f32x2 a = *(const f32x2*)(A_t + dp * 2);
    const f32x2 bb = *(const f32x2*)(Bp + dp * 2);
    scan_pair_sw<true>(buf, dp, a.x, a.y, bb.x, bb.y);
  }
  __syncthreads();

  // ---- P9: combine dir 1 ----
  combine_pass_sw(buf, Mrow, 1, lane, wv, acc2);
  __syncthreads();

  // ---- P10: acc -> OutS in buf ----
  acc_to_outs_sw(acc2, lane, wv, buf);
  __syncthreads();

  // ---- P11: Sh2[b][h][c][w] bf16 (CONTIGUOUS 16 KB stream) ----
  u16* og = Sh2 + (size_t)(b * 128 + h) * 8192;
  for (int i = t; i < 4096; i += 256) {
    const int c = i >> 6, p2 = (i & 63) * 2;
    const f32x2 v = *(const f32x2*)(buf + c * 512 + ((u32)(p2 * 4) ^ ((u32)(((c >> 2) & 7) << 4))));
    *(u32*)(og + c * 128 + p2) = pack2(v.x, v.y);
  }
}

// ---------------- K_B: vertical scans + combine -> Sv2[b][w][c][h] ----------------
__global__ __launch_bounds__(256, 4) void k_B(
    const u16* __restrict__ x_ws, const float* __restrict__ Bp,
    const float* __restrict__ A_t, const u16* __restrict__ Mrow,
    u16* __restrict__ Sv2) {
  char* buf = smem;
  const int t = threadIdx.x;
  const int lane = t & 63, wv = t >> 6;
  const int bid = blockIdx.x, b = bid >> 7, w = bid & 127;

  // ---- stage x column-plane (b,:,w,:): 256B rows, L3-hot reads; stash in regs ----
  uint4 rld[8];
#pragma unroll
  for (int j = 0; j < 8; ++j) {
    const int i = t + j * 256;
    const int row = i >> 4, q = i & 15;
    rld[j] = *(const uint4*)(x_ws + ((size_t)(b * 128 + row) * 128 + w) * 128 + q * 8);
  }
#pragma unroll
  for (int j = 0; j < 8; ++j) {
    const int i = t + j * 256;
    const int row = i >> 4, q = i & 15;
    *(uint4*)(buf + row * 256 + ((u32)(q * 16) ^ ((u32)((row & 7) << 4)))) = rld[j];
  }
  __syncthreads();

  // ---- fwd scan (tb) ----
  if (t < 128 && lane < 32) {
    const int dp = wv * 32 + lane;
    const f32x2 a = *(const f32x2*)(A_t + dp * 2);
    const f32x2 bb = *(const f32x2*)(Bp + dp * 2);
    scan_pair_sw<false>(buf, dp, a.x, a.y, bb.x, bb.y);
  }
  __syncthreads();

  f32x4v acc2[4][2];
#pragma unroll
  for (int i = 0; i < 4; ++i)
#pragma unroll
    for (int j = 0; j < 2; ++j) acc2[i][j] = (f32x4v)0.f;
  combine_pass_sw(buf, Mrow, 2, lane, wv, acc2);
  __syncthreads();

  // ---- restore x from regs ----
#pragma unroll
  for (int j = 0; j < 8; ++j) {
    const int i = t + j * 256;
    const int row = i >> 4, q = i & 15;
    *(uint4*)(buf + row * 256 + ((u32)(q * 16) ^ ((u32)((row & 7) << 4)))) = rld[j];
  }
  __syncthreads();

  // ---- rev scan (bt) ----
  if (t < 128 && lane < 32) {
    const int dp = wv * 32 + lane;
    const f32x2 a = *(const f32x2*)(A_t + dp * 2);
    const f32x2 bb = *(const f32x2*)(Bp + dp * 2);
    scan_pair_sw<true>(buf, dp, a.x, a.y, bb.x, bb.y);
  }
  __syncthreads();

  combine_pass_sw(buf, Mrow, 3, lane, wv, acc2);
  __syncthreads();

  acc_to_outs_sw(acc2, lane, wv, buf);
  __syncthreads();

  // ---- Sv2[b][w][c][h] bf16 (CONTIGUOUS 16 KB stream) ----
  u16* og = Sv2 + (size_t)(b * 128 + w) * 8192;
  for (int i = t; i < 4096; i += 256) {
    const int c = i >> 6, h2 = (i & 63) * 2;
    const f32x2 v = *(const f32x2*)(buf + c * 512 + ((u32)(h2 * 4) ^ ((u32)(((c >> 2) & 7) << 4))));
    *(u32*)(og + c * 128 + h2) = pack2(v.x, v.y);
  }
}

// ---------------- F: out = F_mod + gamma*(S_h + S_v^T + beff) ----------------
__global__ __launch_bounds__(256) void k_final(
    const float* __restrict__ F_in, const float* __restrict__ prior,
    const float* __restrict__ alpha_p, const float* __restrict__ gamma_p,
    const float* __restrict__ beff, const u16* __restrict__ Sv2,
    const u16* __restrict__ Sh2, float* __restrict__ out) {
  u16* Xu = (u16*)smem;
  u32* Xw = (u32*)smem;
  const int t = threadIdx.x;
  const int bid = blockIdx.x, b = bid >> 6, c = bid & 63;
  const size_t base = (size_t)bid * 16384;   // (b,c) plane of out/F

  // stage S_v rows (w-major) for this (b,c): 256B reads, L3-hot
  for (int i = t; i < 2048; i += 256) {
    const int r = i >> 4, j = i & 15;   // r = w
    const uint4 v = *(const uint4*)(Sv2 + ((size_t)(b * 128 + r) * 64 + c) * 128 + j * 8);
    u32* dst = Xw + r * 66 + j * 4;
    dst[0] = v.x; dst[1] = v.y; dst[2] = v.z; dst[3] = v.w;
  }
  __syncthreads();
  const float alpha = alpha_p[0], gamma = gamma_p[0];
  const float be = beff[c];
  for (int i = t; i < 2048; i += 256) {
    const int hh = i >> 4, w8 = (i & 15) * 8;
    float sv[8];
#pragma unroll
    for (int q = 0; q < 8; ++q) sv[q] = bf2f(Xu[(w8 + q) * XS + hh]);
    const size_t off = base + hh * 128 + w8;
    const float* Fp = F_in + off;
    const u16* Sp = Sh2 + (size_t)(b * 128 + hh) * 8192 + c * 128 + w8;
    float* Op = out + off;
    const float* Pp = prior + (b * 128 + hh) * 128 + w8;
    const uint4 sh4 = *(const uint4*)(Sp);
    const u16* sh8 = (const u16*)&sh4;
#pragma unroll
    for (int q = 0; q < 8; ++q) {
      Op[q] = Fp[q] + alpha * Pp[q] + gamma * (bf2f(sh8[q]) + be + sv[q]);
    }
  }
}

extern "C" void kernel_launch(void* const* d_in, const int* in_sizes, int n_in,
                              void* d_out, int out_size, void* d_ws, size_t ws_size,
                              hipStream_t stream) {
  const float* F_in   = (const float*)d_in[0];
  const float* prior  = (const float*)d_in[1];
  const float* Wi     = (const float*)d_in[2];
  const float* bi     = (const float*)d_in[3];
  const float* A_par  = (const float*)d_in[4];
  const float* B_par  = (const float*)d_in[5];
  const float* alpha  = (const float*)d_in[6];
  const float* gamma  = (const float*)d_in[7];
  const float* Wf     = (const float*)d_in[8];
  const float* bf_    = (const float*)d_in[9];
  const float* Wo     = (const float*)d_in[10];
  const float* bo     = (const float*)d_in[11];
  float* out = (float*)d_out;

  char* ws = (char*)d_ws;
  float* A_t   = (float*)ws;                       // 512 B
  float* beff  = (float*)(ws + 512);               // 256 B
  u16*   Mrow  = (u16*)(ws + 1024);                // 64 KB: [4][64][128] bf16
  u16*   x_ws  = (u16*)(ws + 66560);               // 33.5 MB: x[b][h][w][d] bf16
  u16*   Sh2   = (u16*)(ws + 66560 + 33554432);    // 16.8 MB: [b][h][c][w] bf16
  u16*   Sv2   = (u16*)(ws + 66560 + 50331648);    // 16.8 MB: [b][w][c][h] bf16

  hipFuncSetAttribute((const void*)k_A, hipFuncAttributeMaxDynamicSharedMemorySize, SCAN_LDS);
  hipFuncSetAttribute((const void*)k_B, hipFuncAttributeMaxDynamicSharedMemorySize, SCAN_LDS);

  k_pre  <<<129, 256, 0, stream>>>(Wf, Wo, bf_, bo, A_par, A_t, beff, Mrow);
  k_A    <<<1024, 256, SCAN_LDS, stream>>>(F_in, prior, Wi, bi, B_par, alpha, A_t, Mrow, x_ws, Sh2);
  k_B    <<<1024, 256, SCAN_LDS, stream>>>(x_ws, B_par, A_t, Mrow, Sv2);
  k_final<<<512, 256, LDS_X, stream>>>(F_in, prior, alpha, gamma, beff, Sv2, Sh2, out);
}

// Round 10
// 108.743 us; speedup vs baseline: 1.1661x; 1.0453x over previous
//
#include <hip/hip_runtime.h>
#include <hip/hip_bf16.h>

typedef unsigned int u32;
typedef unsigned short u16;
typedef float f32x2 __attribute__((ext_vector_type(2)));
typedef float f32x4 __attribute__((ext_vector_type(4)));
using bf16x8 = __attribute__((ext_vector_type(8))) short;   // MFMA A/B frag (4 VGPRs)
using f32x4v = __attribute__((ext_vector_type(4))) float;   // MFMA C/D frag

#define DEVINL __device__ __forceinline__

// Problem constants: B=8, C=64, D=128, H=128, W=128
// d-split: each k_A/k_B block handles 64 channels (e = 0 or 1).
constexpr int SCAN_LDS = 32768;        // bufA(16K) + bufB(16K); also OutS f32 [64][512B]
constexpr int XS = 132;                // k_final transpose staging stride (u16)
constexpr int LDS_X = 128 * XS * 2;    // 33792

DEVINL float bf2f(u16 u) { union { u32 i; float f; } v; v.i = ((u32)u) << 16; return v.f; }
DEVINL float bf2f_lo(u32 u) { union { u32 i; float f; } v; v.i = u << 16; return v.f; }
DEVINL float bf2f_hi(u32 u) { union { u32 i; float f; } v; v.i = u & 0xffff0000u; return v.f; }
// HW-path bf16 conversion (RNE): compiler emits native cvt (guide m240).
DEVINL u16 f2bf(float f) {
  __hip_bfloat16 h = __float2bfloat16(f);
  u16 r; __builtin_memcpy(&r, &h, 2); return r;
}
DEVINL u32 pack2(float a, float b) { return (u32)f2bf(a) | ((u32)f2bf(b) << 16); }

// ---------------- P0: A=tanh(A_param), Mrow[dir][c][d] bf16, beff, Wi_bf ----------------
__global__ __launch_bounds__(256) void k_pre(
    const float* __restrict__ Wf, const float* __restrict__ Wo,
    const float* __restrict__ bf_, const float* __restrict__ bo,
    const float* __restrict__ A_param, const float* __restrict__ Wi,
    float* __restrict__ A_t, float* __restrict__ beff,
    u16* __restrict__ Mrow, u16* __restrict__ Wi_bf) {
  const int wg = blockIdx.x, t = threadIdx.x;
  if (wg < 128) {
    const int idx = wg * 256 + t;          // 0..32767
    const int cout = idx >> 9;             // 0..63
    const int k = idx & 511;               // dir*128 + d
    float s = 0.f;
    for (int d = 0; d < 128; ++d) s = fmaf(Wo[cout * 128 + d], Wf[d * 512 + k], s);
    const int dir = k >> 7, dm = k & 127;
    Mrow[(dir * 64 + cout) * 128 + dm] = f2bf(s);
  } else if (wg == 128) {
    if (t < 128) A_t[t] = tanhf(A_param[t]);
    if (t < 64) {
      float s = bo[t];
      for (int d = 0; d < 128; ++d) s = fmaf(Wo[t * 128 + d], bf_[d], s);
      beff[t] = s;
    }
  } else {
    // Wi[128 d][64 c] f32 -> bf16, same layout
#pragma unroll
    for (int k = 0; k < 32; ++k) {
      const int i = t + k * 256;
      Wi_bf[i] = f2bf(Wi[i]);
    }
  }
}

extern __shared__ char smem[];

// In-place scan of a d-pair column (u32 = 2 bf16) in a [128][128B] swizzled buffer.
template <bool REV>
DEVINL void scan_col128(char* buf, int dp, float A0, float A1, float B0, float B1) {
  float h0 = 0.f, h1 = 0.f;
  const u32 cb = (u32)(dp * 4);
  u32 nx[8];
#pragma unroll
  for (int j = 0; j < 8; ++j) {
    const int i = REV ? (127 - j) : j;
    nx[j] = *(const u32*)(buf + i * 128 + (cb ^ ((u32)((i & 7) << 4))));
  }
  for (int ib = 0; ib < 128; ib += 8) {
    u32 cur[8];
#pragma unroll
    for (int j = 0; j < 8; ++j) cur[j] = nx[j];
    if (ib + 8 < 128) {
#pragma unroll
      for (int j = 0; j < 8; ++j) {
        const int i = REV ? (127 - (ib + 8 + j)) : (ib + 8 + j);
        nx[j] = *(const u32*)(buf + i * 128 + (cb ^ ((u32)((i & 7) << 4))));
      }
    }
#pragma unroll
    for (int j = 0; j < 8; ++j) {
      const int i = REV ? (127 - (ib + j)) : (ib + j);
      h0 = fmaf(A0, h0, B0 * bf2f_lo(cur[j]));
      h1 = fmaf(A1, h1, B1 * bf2f_hi(cur[j]));
      *(u32*)(buf + i * 128 + (cb ^ ((u32)((i & 7) << 4)))) = pack2(h0, h1);
    }
  }
}

// acc2 += M[dir][:, e*64..e*64+64) @ h (h in swizzled [128 pos][128B] buf).
DEVINL void combine64(const char* buf, const u16* __restrict__ Mrow, int dir, int e,
                      int lane, int wv, f32x4v (&acc2)[4][2]) {
  const int l15 = lane & 15, kg = lane >> 4;
#pragma unroll
  for (int ks = 0; ks < 2; ++ks) {
    bf16x8 afr[4], bfr[2];
#pragma unroll
    for (int ct = 0; ct < 4; ++ct)
      afr[ct] = *(const bf16x8*)(Mrow + ((size_t)dir * 64 + ct * 16 + l15) * 128 + e * 64 + ks * 32 + kg * 8);
#pragma unroll
    for (int pt = 0; pt < 2; ++pt) {
      const int row = wv * 32 + pt * 16 + l15;
      bfr[pt] = *(const bf16x8*)(buf + row * 128 + ((u32)(ks * 64 + kg * 16) ^ ((u32)((row & 7) << 4))));
    }
#pragma unroll
    for (int ct = 0; ct < 4; ++ct)
#pragma unroll
      for (int pt = 0; pt < 2; ++pt)
        acc2[ct][pt] = __builtin_amdgcn_mfma_f32_16x16x32_bf16(afr[ct], bfr[pt], acc2[ct][pt], 0, 0, 0);
  }
}

// Store combine acc into smem as f32 [64 c][512B swz rows] (spans bufA+bufB).
DEVINL void acc_to_outs(const f32x4v (&acc2)[4][2], int lane, int wv, char* buf) {
  const int l15 = lane & 15, kg = lane >> 4;
#pragma unroll
  for (int ct = 0; ct < 4; ++ct)
#pragma unroll
    for (int pt = 0; pt < 2; ++pt)
#pragma unroll
      for (int r = 0; r < 4; ++r) {
        const int row = ct * 16 + kg * 4 + r;
        const int col = wv * 32 + pt * 16 + l15;
        *(float*)(buf + row * 512 + ((u32)(col * 4) ^ ((u32)((row & 7) << 4)))) = acc2[ct][pt][r];
      }
}

// Epilogue: OutS -> partial [64 c][128 pos] bf16 stream (16 KB).
DEVINL void outs_to_global(const char* buf, u16* __restrict__ og, int t) {
#pragma unroll
  for (int j = 0; j < 16; ++j) {
    const int i = t + j * 256;
    const int c = i >> 6, p2 = (i & 63) * 2;
    const f32x2 v = *(const f32x2*)(buf + c * 512 + ((u32)(p2 * 4) ^ ((u32)((c & 7) << 4))));
    *(u32*)(og + c * 128 + p2) = pack2(v.x, v.y);
  }
}

// ---------------- K_A: x-GEMM (64 d half) + horizontal scans + combine ----------------
// bid = ((b*128)+h)*2+e. Writes x2[bid][w][64] and Shp[bid][c][w] (both 16 KB streams).
__global__ __launch_bounds__(256, 5) void k_A(
    const float* __restrict__ F_in, const float* __restrict__ prior,
    const u16* __restrict__ Wi_bf, const float* __restrict__ bi,
    const float* __restrict__ Bp, const float* __restrict__ alpha_p,
    const float* __restrict__ A_t, const u16* __restrict__ Mrow,
    u16* __restrict__ x2, u16* __restrict__ Shp) {
  char* bufA = smem;            // 16 KB [128][128B] swz: FT -> h_lr
  char* bufB = smem + 16384;    // 16 KB: x -> h_rl

  const int t = threadIdx.x;
  const int lane = t & 63, wv = t >> 6, l15 = lane & 15, kg = lane >> 4;
  const int bid = blockIdx.x;
  const int b = bid >> 8, h = (bid >> 1) & 127, e = bid & 1;

  // ---- P1: stage Fmod^T bf16 into bufA: row w = 64 c (128B), swz ----
  {
    const int w = t & 127, ch = t >> 7;
    const float alpha = alpha_p[0];
    const float pv = prior[(b * 128 + h) * 128 + w];
    const float* Fb = F_in + ((size_t)b * 64 + ch * 32) * 16384 + h * 128 + w;
    const u32 sw = (u32)((w & 7) << 4);
    char* rowp = bufA + w * 128;
#pragma unroll
    for (int q = 0; q < 4; ++q) {
      float fv[8];
#pragma unroll
      for (int j = 0; j < 8; ++j) fv[j] = fmaf(alpha, pv, Fb[(q * 8 + j) * 16384]);
      uint4 pk;
      pk.x = pack2(fv[0], fv[1]); pk.y = pack2(fv[2], fv[3]);
      pk.z = pack2(fv[4], fv[5]); pk.w = pack2(fv[6], fv[7]);
      *(uint4*)(rowp + ((u32)(ch * 64 + q * 16) ^ sw)) = pk;
    }
  }
  __syncthreads();

  // ---- P2: A-frags (Fmod rows) into regs ----
  bf16x8 aF[2][2];   // [ks][mt]
#pragma unroll
  for (int ks = 0; ks < 2; ++ks)
#pragma unroll
    for (int mt = 0; mt < 2; ++mt) {
      const int row = wv * 32 + mt * 16 + l15;
      aF[ks][mt] = *(const bf16x8*)(bufA + row * 128 + ((u32)(ks * 64 + kg * 16) ^ ((u32)((row & 7) << 4))));
    }
  __syncthreads();

  // ---- P3: GEMM (64 d half, Wi_bf direct frags); x -> bufA AND bufB ----
  {
    f32x4v acc[2][4];
#pragma unroll
    for (int mt = 0; mt < 2; ++mt)
#pragma unroll
      for (int nt = 0; nt < 4; ++nt) {
        const float bv = bi[e * 64 + nt * 16 + l15];
        acc[mt][nt] = (f32x4v){ bv, bv, bv, bv };
      }
#pragma unroll
    for (int ks = 0; ks < 2; ++ks)
#pragma unroll
      for (int nt = 0; nt < 4; ++nt) {
        const bf16x8 bWi = *(const bf16x8*)(Wi_bf + (e * 64 + nt * 16 + l15) * 64 + ks * 32 + kg * 8);
        acc[0][nt] = __builtin_amdgcn_mfma_f32_16x16x32_bf16(aF[ks][0], bWi, acc[0][nt], 0, 0, 0);
        acc[1][nt] = __builtin_amdgcn_mfma_f32_16x16x32_bf16(aF[ks][1], bWi, acc[1][nt], 0, 0, 0);
      }
#pragma unroll
    for (int mt = 0; mt < 2; ++mt)
#pragma unroll
      for (int nt = 0; nt < 4; ++nt)
#pragma unroll
        for (int r = 0; r < 4; ++r) {
          const int w = wv * 32 + mt * 16 + kg * 4 + r;
          const u32 col = (u32)((nt * 16 + l15) * 2) ^ ((u32)((w & 7) << 4));
          const u16 v = f2bf(acc[mt][nt][r]);
          *(u16*)(bufA + w * 128 + col) = v;
          *(u16*)(bufB + w * 128 + col) = v;
        }
  }
  __syncthreads();

  // ---- P4: x -> global (16 KB stream) ----
  {
    u16* xg = x2 + (size_t)bid * 8192;
#pragma unroll
    for (int j = 0; j < 4; ++j) {
      const int idx = t + j * 256;
      const int row = idx >> 3, q = idx & 7;
      const uint4 v = *(const uint4*)(bufB + row * 128 + ((u32)(q * 16) ^ ((u32)((row & 7) << 4))));
      *(uint4*)(xg + row * 64 + q * 8) = v;
    }
  }
  __syncthreads();

  // ---- P5: concurrent scans: wave0 fwd on bufA, wave1 rev on bufB ----
  if (wv < 2 && lane < 32) {
    const int dgp = e * 64 + lane * 2;
    const f32x2 a = *(const f32x2*)(A_t + dgp);
    const f32x2 bb = *(const f32x2*)(Bp + dgp);
    if (wv == 0) scan_col128<false>(bufA, lane, a.x, a.y, bb.x, bb.y);
    else         scan_col128<true >(bufB, lane, a.x, a.y, bb.x, bb.y);
  }
  __syncthreads();

  // ---- P6: combine dir0 (bufA) + dir1 (bufB) ----
  f32x4v acc2[4][2];
#pragma unroll
  for (int i = 0; i < 4; ++i)
#pragma unroll
    for (int j = 0; j < 2; ++j) acc2[i][j] = (f32x4v)0.f;
  combine64(bufA, Mrow, 0, e, lane, wv, acc2);
  combine64(bufB, Mrow, 1, e, lane, wv, acc2);
  __syncthreads();

  // ---- P7: acc -> OutS (32 KB f32 spanning both buffers) ----
  acc_to_outs(acc2, lane, wv, smem);
  __syncthreads();

  // ---- P8: Shp[bid][c][w] (16 KB stream) ----
  outs_to_global(smem, Shp + (size_t)bid * 8192, t);
}

// ---------------- K_B: vertical scans + combine -> Svp[bid][c][h] ----------------
// bid = ((b*128)+w)*2+e.
__global__ __launch_bounds__(256, 5) void k_B(
    const u16* __restrict__ x2, const float* __restrict__ Bp,
    const float* __restrict__ A_t, const u16* __restrict__ Mrow,
    u16* __restrict__ Svp) {
  char* bufA = smem;
  char* bufB = smem + 16384;
  const int t = threadIdx.x;
  const int lane = t & 63, wv = t >> 6;
  const int bid = blockIdx.x;
  const int b = bid >> 8, w = (bid >> 1) & 127, e = bid & 1;

  // ---- P1: stage x rows (h-major) into both buffers; 128B L3-hot segments ----
#pragma unroll
  for (int j = 0; j < 4; ++j) {
    const int idx = t + j * 256;
    const int hh = idx >> 3, q = idx & 7;
    const uint4 v = *(const uint4*)(x2 + ((size_t)((b * 128 + hh) * 2 + e)) * 8192 + w * 64 + q * 8);
    const u32 col = (u32)(q * 16) ^ ((u32)((hh & 7) << 4));
    *(uint4*)(bufA + hh * 128 + col) = v;
    *(uint4*)(bufB + hh * 128 + col) = v;
  }
  __syncthreads();

  // ---- P2: concurrent scans: wave0 fwd (tb) bufA, wave1 rev (bt) bufB ----
  if (wv < 2 && lane < 32) {
    const int dgp = e * 64 + lane * 2;
    const f32x2 a = *(const f32x2*)(A_t + dgp);
    const f32x2 bb = *(const f32x2*)(Bp + dgp);
    if (wv == 0) scan_col128<false>(bufA, lane, a.x, a.y, bb.x, bb.y);
    else         scan_col128<true >(bufB, lane, a.x, a.y, bb.x, bb.y);
  }
  __syncthreads();

  // ---- P3: combine dir2 (bufA) + dir3 (bufB) ----
  f32x4v acc2[4][2];
#pragma unroll
  for (int i = 0; i < 4; ++i)
#pragma unroll
    for (int j = 0; j < 2; ++j) acc2[i][j] = (f32x4v)0.f;
  combine64(bufA, Mrow, 2, e, lane, wv, acc2);
  combine64(bufB, Mrow, 3, e, lane, wv, acc2);
  __syncthreads();

  // ---- P4: acc -> OutS ----
  acc_to_outs(acc2, lane, wv, smem);
  __syncthreads();

  // ---- P5: Svp[bid][c][h] (16 KB stream) ----
  outs_to_global(smem, Svp + (size_t)bid * 8192, t);
}

// ---------------- F: out = F_mod + gamma*(Sh0+Sh1 + (Sv0+Sv1)^T + beff) ----------------
__global__ __launch_bounds__(256) void k_final(
    const float* __restrict__ F_in, const float* __restrict__ prior,
    const float* __restrict__ alpha_p, const float* __restrict__ gamma_p,
    const float* __restrict__ beff, const u16* __restrict__ Svp,
    const u16* __restrict__ Shp, float* __restrict__ out) {
  u16* Xu = (u16*)smem;
  const int t = threadIdx.x;
  const int bid = blockIdx.x, b = bid >> 6, c = bid & 63;
  const size_t base = (size_t)bid * 16384;   // (b,c) plane of out/F

  // stage Sv = Svp(e0)+Svp(e1), transposed via LDS: Xu[w][h], stride 132
  for (int i = t; i < 2048; i += 256) {
    const int w = i >> 4, q = i & 15;
    const u16* s0 = Svp + ((size_t)((b * 128 + w) * 2)) * 8192 + c * 128 + q * 8;
    const uint4 a4 = *(const uint4*)(s0);
    const uint4 b4 = *(const uint4*)(s0 + 8192);
    const u16* ap = (const u16*)&a4;
    const u16* bp = (const u16*)&b4;
    u32* dst = (u32*)(Xu + w * 132 + q * 8);
#pragma unroll
    for (int k = 0; k < 4; ++k) {
      const float lo = bf2f(ap[k * 2]) + bf2f(bp[k * 2]);
      const float hi = bf2f(ap[k * 2 + 1]) + bf2f(bp[k * 2 + 1]);
      dst[k] = pack2(lo, hi);
    }
  }
  __syncthreads();
  const float alpha = alpha_p[0], gamma = gamma_p[0];
  const float be = beff[c];
  for (int i = t; i < 2048; i += 256) {
    const int hh = i >> 4, w8 = (i & 15) * 8;
    const size_t off = base + hh * 128 + w8;
    const u16* sh0 = Shp + ((size_t)((b * 128 + hh) * 2)) * 8192 + c * 128 + w8;
    const uint4 g0 = *(const uint4*)(sh0);
    const uint4 g1 = *(const uint4*)(sh0 + 8192);
    const u16* p0 = (const u16*)&g0;
    const u16* p1 = (const u16*)&g1;
    const float* Fp = F_in + off;
    float* Op = out + off;
    const float* Pp = prior + (b * 128 + hh) * 128 + w8;
#pragma unroll
    for (int q = 0; q < 8; ++q) {
      const float sv = bf2f(Xu[(w8 + q) * 132 + hh]);
      Op[q] = Fp[q] + alpha * Pp[q] + gamma * (bf2f(p0[q]) + bf2f(p1[q]) + sv + be);
    }
  }
}

extern "C" void kernel_launch(void* const* d_in, const int* in_sizes, int n_in,
                              void* d_out, int out_size, void* d_ws, size_t ws_size,
                              hipStream_t stream) {
  const float* F_in   = (const float*)d_in[0];
  const float* prior  = (const float*)d_in[1];
  const float* Wi     = (const float*)d_in[2];
  const float* bi     = (const float*)d_in[3];
  const float* A_par  = (const float*)d_in[4];
  const float* B_par  = (const float*)d_in[5];
  const float* alpha  = (const float*)d_in[6];
  const float* gamma  = (const float*)d_in[7];
  const float* Wf     = (const float*)d_in[8];
  const float* bf_    = (const float*)d_in[9];
  const float* Wo     = (const float*)d_in[10];
  const float* bo     = (const float*)d_in[11];
  float* out = (float*)d_out;

  char* ws = (char*)d_ws;
  float* A_t   = (float*)ws;                        // 512 B
  float* beff  = (float*)(ws + 512);                // 256 B
  u16*   Mrow  = (u16*)(ws + 1024);                 // 64 KB: [4][64][128] bf16
  u16*   Wi_bf = (u16*)(ws + 66560);                // 16 KB: [128][64] bf16
  u16*   x2    = (u16*)(ws + 82944);                // 33.5 MB: [2048][128 w][64 d]
  u16*   Shp   = (u16*)(ws + 82944 + 33554432);     // 33.5 MB: [2048][64 c][128 w]
  u16*   Svp   = (u16*)(ws + 82944 + 67108864);     // 33.5 MB: [2048][64 c][128 h]

  hipFuncSetAttribute((const void*)k_A, hipFuncAttributeMaxDynamicSharedMemorySize, SCAN_LDS);
  hipFuncSetAttribute((const void*)k_B, hipFuncAttributeMaxDynamicSharedMemorySize, SCAN_LDS);

  k_pre  <<<130, 256, 0, stream>>>(Wf, Wo, bf_, bo, A_par, Wi, A_t, beff, Mrow, Wi_bf);
  k_A    <<<2048, 256, SCAN_LDS, stream>>>(F_in, prior, Wi_bf, bi, B_par, alpha, A_t, Mrow, x2, Shp);
  k_B    <<<2048, 256, SCAN_LDS, stream>>>(x2, B_par, A_t, Mrow, Svp);
  k_final<<<512, 256, LDS_X, stream>>>(F_in, prior, alpha, gamma, beff, Svp, Shp, out);
}

// Round 11
// 98.607 us; speedup vs baseline: 1.2860x; 1.1028x over previous
//
#include <hip/hip_runtime.h>
#include <hip/hip_bf16.h>

typedef unsigned int u32;
typedef unsigned short u16;
typedef float f32x2 __attribute__((ext_vector_type(2)));
typedef float f32x4 __attribute__((ext_vector_type(4)));
using bf16x8 = __attribute__((ext_vector_type(8))) short;   // MFMA A/B frag (4 VGPRs)
using f32x4v = __attribute__((ext_vector_type(4))) float;   // MFMA C/D frag

#define DEVINL __device__ __forceinline__

// Problem constants: B=8, C=64, D=128, H=128, W=128
// d-split: each k_A/k_B block handles 64 channels (e = 0 or 1).
constexpr int SCAN_LDS = 32768;        // bufA(16K) + bufB(16K); also OutS f32 [64][512B]
constexpr int XS = 132;                // k_final transpose staging stride (u16)
constexpr int LDS_X = 128 * XS * 2;    // 33792

DEVINL float bf2f(u16 u) { union { u32 i; float f; } v; v.i = ((u32)u) << 16; return v.f; }
DEVINL float bf2f_lo(u32 u) { union { u32 i; float f; } v; v.i = u << 16; return v.f; }
DEVINL float bf2f_hi(u32 u) { union { u32 i; float f; } v; v.i = u & 0xffff0000u; return v.f; }
DEVINL u16 f2bf(float f) {
  __hip_bfloat16 h = __float2bfloat16(f);
  u16 r; __builtin_memcpy(&r, &h, 2); return r;
}
DEVINL u32 pack2(float a, float b) { return (u32)f2bf(a) | ((u32)f2bf(b) << 16); }

// ---------------- P0: A=tanh(A_param), Mrow[dir][c][d] bf16, beff, Wi_bf ----------------
__global__ __launch_bounds__(256) void k_pre(
    const float* __restrict__ Wf, const float* __restrict__ Wo,
    const float* __restrict__ bf_, const float* __restrict__ bo,
    const float* __restrict__ A_param, const float* __restrict__ Wi,
    float* __restrict__ A_t, float* __restrict__ beff,
    u16* __restrict__ Mrow, u16* __restrict__ Wi_bf) {
  const int wg = blockIdx.x, t = threadIdx.x;
  if (wg < 128) {
    const int idx = wg * 256 + t;          // 0..32767
    const int cout = idx >> 9;             // 0..63
    const int k = idx & 511;               // dir*128 + d
    float s = 0.f;
    for (int d = 0; d < 128; ++d) s = fmaf(Wo[cout * 128 + d], Wf[d * 512 + k], s);
    const int dir = k >> 7, dm = k & 127;
    Mrow[(dir * 64 + cout) * 128 + dm] = f2bf(s);
  } else if (wg == 128) {
    if (t < 128) A_t[t] = tanhf(A_param[t]);
    if (t < 64) {
      float s = bo[t];
      for (int d = 0; d < 128; ++d) s = fmaf(Wo[t * 128 + d], bf_[d], s);
      beff[t] = s;
    }
  } else {
    // Wi[128 d][64 c] f32 -> bf16, same layout
#pragma unroll
    for (int k = 0; k < 32; ++k) {
      const int i = t + k * 256;
      Wi_bf[i] = f2bf(Wi[i]);
    }
  }
}

extern __shared__ char smem[];

// ---- Chunked scan: local pass. buf = [128 pos][128B] swz; dp = u32 pair column.
// Chunk covers scan-order indices [chunk*32, chunk*32+32). REV maps scan index i2 -> pos 127-i2.
template <bool REV>
DEVINL void scan_local(char* buf, int dp, int chunk, float A0, float A1, float B0, float B1) {
  float h0 = 0.f, h1 = 0.f;
  const u32 cb = (u32)(dp * 4);
  const int s = chunk * 32;
  u32 nx[8];
#pragma unroll
  for (int j = 0; j < 8; ++j) {
    const int i = REV ? (127 - (s + j)) : (s + j);
    nx[j] = *(const u32*)(buf + i * 128 + (cb ^ ((u32)((i & 7) << 4))));
  }
  for (int ib = 0; ib < 32; ib += 8) {
    u32 cur[8];
#pragma unroll
    for (int j = 0; j < 8; ++j) cur[j] = nx[j];
    if (ib + 8 < 32) {
#pragma unroll
      for (int j = 0; j < 8; ++j) {
        const int i2 = s + ib + 8 + j;
        const int i = REV ? (127 - i2) : i2;
        nx[j] = *(const u32*)(buf + i * 128 + (cb ^ ((u32)((i & 7) << 4))));
      }
    }
#pragma unroll
    for (int j = 0; j < 8; ++j) {
      const int i2 = s + ib + j;
      const int i = REV ? (127 - i2) : i2;
      h0 = fmaf(A0, h0, B0 * bf2f_lo(cur[j]));
      h1 = fmaf(A1, h1, B1 * bf2f_hi(cur[j]));
      *(u32*)(buf + i * 128 + (cb ^ ((u32)((i & 7) << 4)))) = pack2(h0, h1);
    }
  }
}

// ---- Chunked scan: carry correction. h_i = l_i + A^{j+1} * C, C from l_end rows in LDS.
template <bool REV>
DEVINL void scan_fix(char* buf, int dp, int chunk, float A0, float A1) {
  if (chunk == 0) return;
  float q0 = A0, q1 = A1;
#pragma unroll
  for (int k = 0; k < 5; ++k) { q0 *= q0; q1 *= q1; }   // A^32
  const u32 cb = (u32)(dp * 4);
  float C0 = 0.f, C1 = 0.f;
  for (int k = 0; k < chunk; ++k) {
    const int i2 = k * 32 + 31;
    const int i = REV ? (127 - i2) : i2;
    const u32 v = *(const u32*)(buf + i * 128 + (cb ^ ((u32)((i & 7) << 4))));
    C0 = fmaf(C0, q0, bf2f_lo(v));
    C1 = fmaf(C1, q1, bf2f_hi(v));
  }
  float p0 = A0, p1 = A1;
  const int s = chunk * 32;
  u32 nx[8];
#pragma unroll
  for (int j = 0; j < 8; ++j) {
    const int i = REV ? (127 - (s + j)) : (s + j);
    nx[j] = *(const u32*)(buf + i * 128 + (cb ^ ((u32)((i & 7) << 4))));
  }
  for (int ib = 0; ib < 32; ib += 8) {
    u32 cur[8];
#pragma unroll
    for (int j = 0; j < 8; ++j) cur[j] = nx[j];
    if (ib + 8 < 32) {
#pragma unroll
      for (int j = 0; j < 8; ++j) {
        const int i2 = s + ib + 8 + j;
        const int i = REV ? (127 - i2) : i2;
        nx[j] = *(const u32*)(buf + i * 128 + (cb ^ ((u32)((i & 7) << 4))));
      }
    }
#pragma unroll
    for (int j = 0; j < 8; ++j) {
      const int i2 = s + ib + j;
      const int i = REV ? (127 - i2) : i2;
      const float h0 = fmaf(p0, C0, bf2f_lo(cur[j]));
      const float h1 = fmaf(p1, C1, bf2f_hi(cur[j]));
      *(u32*)(buf + i * 128 + (cb ^ ((u32)((i & 7) << 4)))) = pack2(h0, h1);
      p0 *= A0; p1 *= A1;
    }
  }
}

// Both scans for a block: dir0 = fwd on bufA, dir1 = rev on bufB; 4 chunks each.
DEVINL void run_scans(char* bufA, char* bufB, int t, int e,
                      const float* __restrict__ A_t, const float* __restrict__ Bp) {
  const int dp = t & 31, chunk = (t >> 5) & 3, dir = t >> 7;
  const int dgp = e * 64 + dp * 2;
  const f32x2 a = *(const f32x2*)(A_t + dgp);
  const f32x2 bb = *(const f32x2*)(Bp + dgp);
  char* sb = dir ? bufB : bufA;
  if (dir == 0) scan_local<false>(sb, dp, chunk, a.x, a.y, bb.x, bb.y);
  else          scan_local<true >(sb, dp, chunk, a.x, a.y, bb.x, bb.y);
  __syncthreads();
  if (dir == 0) scan_fix<false>(sb, dp, chunk, a.x, a.y);
  else          scan_fix<true >(sb, dp, chunk, a.x, a.y);
}

// acc2 += M[dir][:, e*64..e*64+64) @ h (h in swizzled [128 pos][128B] buf).
DEVINL void combine64(const char* buf, const u16* __restrict__ Mrow, int dir, int e,
                      int lane, int wv, f32x4v (&acc2)[4][2]) {
  const int l15 = lane & 15, kg = lane >> 4;
#pragma unroll
  for (int ks = 0; ks < 2; ++ks) {
    bf16x8 afr[4], bfr[2];
#pragma unroll
    for (int ct = 0; ct < 4; ++ct)
      afr[ct] = *(const bf16x8*)(Mrow + ((size_t)dir * 64 + ct * 16 + l15) * 128 + e * 64 + ks * 32 + kg * 8);
#pragma unroll
    for (int pt = 0; pt < 2; ++pt) {
      const int row = wv * 32 + pt * 16 + l15;
      bfr[pt] = *(const bf16x8*)(buf + row * 128 + ((u32)(ks * 64 + kg * 16) ^ ((u32)((row & 7) << 4))));
    }
#pragma unroll
    for (int ct = 0; ct < 4; ++ct)
#pragma unroll
      for (int pt = 0; pt < 2; ++pt)
        acc2[ct][pt] = __builtin_amdgcn_mfma_f32_16x16x32_bf16(afr[ct], bfr[pt], acc2[ct][pt], 0, 0, 0);
  }
}

// Store combine acc into smem as f32 [64 c][512B swz rows] (spans bufA+bufB).
DEVINL void acc_to_outs(const f32x4v (&acc2)[4][2], int lane, int wv, char* buf) {
  const int l15 = lane & 15, kg = lane >> 4;
#pragma unroll
  for (int ct = 0; ct < 4; ++ct)
#pragma unroll
    for (int pt = 0; pt < 2; ++pt)
#pragma unroll
      for (int r = 0; r < 4; ++r) {
        const int row = ct * 16 + kg * 4 + r;
        const int col = wv * 32 + pt * 16 + l15;
        *(float*)(buf + row * 512 + ((u32)(col * 4) ^ ((u32)((row & 7) << 4)))) = acc2[ct][pt][r];
      }
}

// Epilogue: OutS -> partial [64 c][128 pos] bf16 stream (16 KB).
DEVINL void outs_to_global(const char* buf, u16* __restrict__ og, int t) {
#pragma unroll
  for (int j = 0; j < 16; ++j) {
    const int i = t + j * 256;
    const int c = i >> 6, p2 = (i & 63) * 2;
    const f32x2 v = *(const f32x2*)(buf + c * 512 + ((u32)(p2 * 4) ^ ((u32)((c & 7) << 4))));
    *(u32*)(og + c * 128 + p2) = pack2(v.x, v.y);
  }
}

// ---------------- K_A: x-GEMM (64 d half) + horizontal scans + combine ----------------
// bid = ((b*128)+h)*2+e. Writes x2[bid][w][64] and Shp[bid][c][w] (both 16 KB streams).
__global__ __launch_bounds__(256, 5) void k_A(
    const float* __restrict__ F_in, const float* __restrict__ prior,
    const u16* __restrict__ Wi_bf, const float* __restrict__ bi,
    const float* __restrict__ Bp, const float* __restrict__ alpha_p,
    const float* __restrict__ A_t, const u16* __restrict__ Mrow,
    u16* __restrict__ x2, u16* __restrict__ Shp) {
  char* bufA = smem;            // 16 KB [128][128B] swz: FT -> x -> h_lr
  char* bufB = smem + 16384;    // 16 KB: x copy -> h_rl

  const int t = threadIdx.x;
  const int lane = t & 63, wv = t >> 6, l15 = lane & 15, kg = lane >> 4;
  const int bid = blockIdx.x;
  const int b = bid >> 8, h = (bid >> 1) & 127, e = bid & 1;

  // ---- P1: stage Fmod^T bf16 into bufA: row w = 64 c (128B), swz ----
  {
    const int w = t & 127, ch = t >> 7;
    const float alpha = alpha_p[0];
    const float pv = prior[(b * 128 + h) * 128 + w];
    const float* Fb = F_in + ((size_t)b * 64 + ch * 32) * 16384 + h * 128 + w;
    const u32 sw = (u32)((w & 7) << 4);
    char* rowp = bufA + w * 128;
#pragma unroll
    for (int q = 0; q < 4; ++q) {
      float fv[8];
#pragma unroll
      for (int j = 0; j < 8; ++j) fv[j] = fmaf(alpha, pv, Fb[(q * 8 + j) * 16384]);
      uint4 pk;
      pk.x = pack2(fv[0], fv[1]); pk.y = pack2(fv[2], fv[3]);
      pk.z = pack2(fv[4], fv[5]); pk.w = pack2(fv[6], fv[7]);
      *(uint4*)(rowp + ((u32)(ch * 64 + q * 16) ^ sw)) = pk;
    }
  }
  __syncthreads();

  // ---- P2: A-frags (Fmod rows) into regs ----
  bf16x8 aF[2][2];   // [ks][mt]
#pragma unroll
  for (int ks = 0; ks < 2; ++ks)
#pragma unroll
    for (int mt = 0; mt < 2; ++mt) {
      const int row = wv * 32 + mt * 16 + l15;
      aF[ks][mt] = *(const bf16x8*)(bufA + row * 128 + ((u32)(ks * 64 + kg * 16) ^ ((u32)((row & 7) << 4))));
    }
  __syncthreads();

  // ---- P3: GEMM (64 d half, Wi_bf direct frags); x -> bufA only ----
  {
    f32x4v acc[2][4];
#pragma unroll
    for (int mt = 0; mt < 2; ++mt)
#pragma unroll
      for (int nt = 0; nt < 4; ++nt) {
        const float bv = bi[e * 64 + nt * 16 + l15];
        acc[mt][nt] = (f32x4v){ bv, bv, bv, bv };
      }
#pragma unroll
    for (int ks = 0; ks < 2; ++ks)
#pragma unroll
      for (int nt = 0; nt < 4; ++nt) {
        const bf16x8 bWi = *(const bf16x8*)(Wi_bf + (e * 64 + nt * 16 + l15) * 64 + ks * 32 + kg * 8);
        acc[0][nt] = __builtin_amdgcn_mfma_f32_16x16x32_bf16(aF[ks][0], bWi, acc[0][nt], 0, 0, 0);
        acc[1][nt] = __builtin_amdgcn_mfma_f32_16x16x32_bf16(aF[ks][1], bWi, acc[1][nt], 0, 0, 0);
      }
#pragma unroll
    for (int mt = 0; mt < 2; ++mt)
#pragma unroll
      for (int nt = 0; nt < 4; ++nt)
#pragma unroll
        for (int r = 0; r < 4; ++r) {
          const int w = wv * 32 + mt * 16 + kg * 4 + r;
          const u32 col = (u32)((nt * 16 + l15) * 2) ^ ((u32)((w & 7) << 4));
          *(u16*)(bufA + w * 128 + col) = f2bf(acc[mt][nt][r]);
        }
  }
  __syncthreads();

  // ---- P4: x -> global (16 KB stream) + bufA -> bufB vector copy ----
  {
    u16* xg = x2 + (size_t)bid * 8192;
#pragma unroll
    for (int j = 0; j < 4; ++j) {
      const int idx = t + j * 256;
      const int row = idx >> 3, q = idx & 7;
      const u32 off = (u32)(q * 16) ^ ((u32)((row & 7) << 4));
      const uint4 v = *(const uint4*)(bufA + row * 128 + off);
      *(uint4*)(xg + row * 64 + q * 8) = v;
      *(uint4*)(bufB + row * 128 + off) = v;
    }
  }
  __syncthreads();

  // ---- P5: chunk-parallel scans (all 256 threads) ----
  run_scans(bufA, bufB, t, e, A_t, Bp);
  __syncthreads();

  // ---- P6: combine dir0 (bufA) + dir1 (bufB) ----
  f32x4v acc2[4][2];
#pragma unroll
  for (int i = 0; i < 4; ++i)
#pragma unroll
    for (int j = 0; j < 2; ++j) acc2[i][j] = (f32x4v)0.f;
  combine64(bufA, Mrow, 0, e, lane, wv, acc2);
  combine64(bufB, Mrow, 1, e, lane, wv, acc2);
  __syncthreads();

  // ---- P7: acc -> OutS (32 KB f32 spanning both buffers) ----
  acc_to_outs(acc2, lane, wv, smem);
  __syncthreads();

  // ---- P8: Shp[bid][c][w] (16 KB stream) ----
  outs_to_global(smem, Shp + (size_t)bid * 8192, t);
}

// ---------------- K_B: vertical scans + combine -> Svp[bid][c][h] ----------------
// bid = ((b*128)+w)*2+e.
__global__ __launch_bounds__(256, 5) void k_B(
    const u16* __restrict__ x2, const float* __restrict__ Bp,
    const float* __restrict__ A_t, const u16* __restrict__ Mrow,
    u16* __restrict__ Svp) {
  char* bufA = smem;
  char* bufB = smem + 16384;
  const int t = threadIdx.x;
  const int lane = t & 63, wv = t >> 6;
  const int bid = blockIdx.x;
  const int b = bid >> 8, w = (bid >> 1) & 127, e = bid & 1;

  // ---- P1: stage x rows (h-major) into both buffers; 128B L3-hot segments ----
#pragma unroll
  for (int j = 0; j < 4; ++j) {
    const int idx = t + j * 256;
    const int hh = idx >> 3, q = idx & 7;
    const uint4 v = *(const uint4*)(x2 + ((size_t)((b * 128 + hh) * 2 + e)) * 8192 + w * 64 + q * 8);
    const u32 col = (u32)(q * 16) ^ ((u32)((hh & 7) << 4));
    *(uint4*)(bufA + hh * 128 + col) = v;
    *(uint4*)(bufB + hh * 128 + col) = v;
  }
  __syncthreads();

  // ---- P2: chunk-parallel scans ----
  run_scans(bufA, bufB, t, e, A_t, Bp);
  __syncthreads();

  // ---- P3: combine dir2 (bufA) + dir3 (bufB) ----
  f32x4v acc2[4][2];
#pragma unroll
  for (int i = 0; i < 4; ++i)
#pragma unroll
    for (int j = 0; j < 2; ++j) acc2[i][j] = (f32x4v)0.f;
  combine64(bufA, Mrow, 2, e, lane, wv, acc2);
  combine64(bufB, Mrow, 3, e, lane, wv, acc2);
  __syncthreads();

  // ---- P4: acc -> OutS ----
  acc_to_outs(acc2, lane, wv, smem);
  __syncthreads();

  // ---- P5: Svp[bid][c][h] (16 KB stream) ----
  outs_to_global(smem, Svp + (size_t)bid * 8192, t);
}

// ---------------- F: out = F_mod + gamma*(Sh0+Sh1 + (Sv0+Sv1)^T + beff) ----------------
__global__ __launch_bounds__(256) void k_final(
    const float* __restrict__ F_in, const float* __restrict__ prior,
    const float* __restrict__ alpha_p, const float* __restrict__ gamma_p,
    const float* __restrict__ beff, const u16* __restrict__ Svp,
    const u16* __restrict__ Shp, float* __restrict__ out) {
  u16* Xu = (u16*)smem;
  const int t = threadIdx.x;
  const int bid = blockIdx.x, b = bid >> 6, c = bid & 63;
  const size_t base = (size_t)bid * 16384;   // (b,c) plane of out/F

  // stage Sv = Svp(e0)+Svp(e1), transposed via LDS: Xu[w][h], stride 132
  for (int i = t; i < 2048; i += 256) {
    const int w = i >> 4, q = i & 15;
    const u16* s0 = Svp + ((size_t)((b * 128 + w) * 2)) * 8192 + c * 128 + q * 8;
    const uint4 a4 = *(const uint4*)(s0);
    const uint4 b4 = *(const uint4*)(s0 + 8192);
    const u16* ap = (const u16*)&a4;
    const u16* bp = (const u16*)&b4;
    u32* dst = (u32*)(Xu + w * 132 + q * 8);
#pragma unroll
    for (int k = 0; k < 4; ++k) {
      const float lo = bf2f(ap[k * 2]) + bf2f(bp[k * 2]);
      const float hi = bf2f(ap[k * 2 + 1]) + bf2f(bp[k * 2 + 1]);
      dst[k] = pack2(lo, hi);
    }
  }
  __syncthreads();
  const float alpha = alpha_p[0], gamma = gamma_p[0];
  const float be = beff[c];
  for (int i = t; i < 2048; i += 256) {
    const int hh = i >> 4, w8 = (i & 15) * 8;
    const size_t off = base + hh * 128 + w8;
    const u16* sh0 = Shp + ((size_t)((b * 128 + hh) * 2)) * 8192 + c * 128 + w8;
    const uint4 g0 = *(const uint4*)(sh0);
    const uint4 g1 = *(const uint4*)(sh0 + 8192);
    const u16* p0 = (const u16*)&g0;
    const u16* p1 = (const u16*)&g1;
    const float* Fp = F_in + off;
    float* Op = out + off;
    const float* Pp = prior + (b * 128 + hh) * 128 + w8;
#pragma unroll
    for (int q = 0; q < 8; ++q) {
      const float sv = bf2f(Xu[(w8 + q) * 132 + hh]);
      Op[q] = Fp[q] + alpha * Pp[q] + gamma * (bf2f(p0[q]) + bf2f(p1[q]) + sv + be);
    }
  }
}

extern "C" void kernel_launch(void* const* d_in, const int* in_sizes, int n_in,
                              void* d_out, int out_size, void* d_ws, size_t ws_size,
                              hipStream_t stream) {
  const float* F_in   = (const float*)d_in[0];
  const float* prior  = (const float*)d_in[1];
  const float* Wi     = (const float*)d_in[2];
  const float* bi     = (const float*)d_in[3];
  const float* A_par  = (const float*)d_in[4];
  const float* B_par  = (const float*)d_in[5];
  const float* alpha  = (const float*)d_in[6];
  const float* gamma  = (const float*)d_in[7];
  const float* Wf     = (const float*)d_in[8];
  const float* bf_    = (const float*)d_in[9];
  const float* Wo     = (const float*)d_in[10];
  const float* bo     = (const float*)d_in[11];
  float* out = (float*)d_out;

  char* ws = (char*)d_ws;
  float* A_t   = (float*)ws;                        // 512 B
  float* beff  = (float*)(ws + 512);                // 256 B
  u16*   Mrow  = (u16*)(ws + 1024);                 // 64 KB: [4][64][128] bf16
  u16*   Wi_bf = (u16*)(ws + 66560);                // 16 KB: [128][64] bf16
  u16*   x2    = (u16*)(ws + 82944);                // 33.5 MB: [2048][128 w][64 d]
  u16*   Shp   = (u16*)(ws + 82944 + 33554432);     // 33.5 MB: [2048][64 c][128 w]
  u16*   Svp   = (u16*)(ws + 82944 + 67108864);     // 33.5 MB: [2048][64 c][128 h]

  hipFuncSetAttribute((const void*)k_A, hipFuncAttributeMaxDynamicSharedMemorySize, SCAN_LDS);
  hipFuncSetAttribute((const void*)k_B, hipFuncAttributeMaxDynamicSharedMemorySize, SCAN_LDS);

  k_pre  <<<130, 256, 0, stream>>>(Wf, Wo, bf_, bo, A_par, Wi, A_t, beff, Mrow, Wi_bf);
  k_A    <<<2048, 256, SCAN_LDS, stream>>>(F_in, prior, Wi_bf, bi, B_par, alpha, A_t, Mrow, x2, Shp);
  k_B    <<<2048, 256, SCAN_LDS, stream>>>(x2, B_par, A_t, Mrow, Svp);
  k_final<<<512, 256, LDS_X, stream>>>(F_in, prior, alpha, gamma, beff, Svp, Shp, out);
}

// Round 12
// 98.134 us; speedup vs baseline: 1.2922x; 1.0048x over previous
//
#include <hip/hip_runtime.h>
#include <hip/hip_bf16.h>

typedef unsigned int u32;
typedef unsigned short u16;
typedef float f32x2 __attribute__((ext_vector_type(2)));
typedef float f32x4 __attribute__((ext_vector_type(4)));
using bf16x8 = __attribute__((ext_vector_type(8))) short;   // MFMA A/B frag (4 VGPRs)
using f32x4v = __attribute__((ext_vector_type(4))) float;   // MFMA C/D frag

#define DEVINL __device__ __forceinline__

// Problem constants: B=8, C=64, D=128, H=128, W=128
// d-split: each k_A/k_B block handles 64 channels (e = 0 or 1).
constexpr int SCAN_LDS = 32768;        // bufA(16K) + bufB(16K); also OutS f32 [64][512B]
constexpr int XS = 132;                // k_final transpose staging stride (u16)
constexpr int LDS_X = 128 * XS * 2;    // 33792

DEVINL float bf2f(u16 u) { union { u32 i; float f; } v; v.i = ((u32)u) << 16; return v.f; }
DEVINL float bf2f_lo(u32 u) { union { u32 i; float f; } v; v.i = u << 16; return v.f; }
DEVINL float bf2f_hi(u32 u) { union { u32 i; float f; } v; v.i = u & 0xffff0000u; return v.f; }
DEVINL u16 f2bf(float f) {
  __hip_bfloat16 h = __float2bfloat16(f);
  u16 r; __builtin_memcpy(&r, &h, 2); return r;
}
DEVINL u32 pack2(float a, float b) { return (u32)f2bf(a) | ((u32)f2bf(b) << 16); }

// ---------------- P0: A=tanh(A_param), Mrow[dir][c][d] bf16, beff, Wi_bf ----------------
__global__ __launch_bounds__(256) void k_pre(
    const float* __restrict__ Wf, const float* __restrict__ Wo,
    const float* __restrict__ bf_, const float* __restrict__ bo,
    const float* __restrict__ A_param, const float* __restrict__ Wi,
    float* __restrict__ A_t, float* __restrict__ beff,
    u16* __restrict__ Mrow, u16* __restrict__ Wi_bf) {
  const int wg = blockIdx.x, t = threadIdx.x;
  if (wg < 128) {
    const int idx = wg * 256 + t;          // 0..32767
    const int cout = idx >> 9;             // 0..63
    const int k = idx & 511;               // dir*128 + d
    float s = 0.f;
    for (int d = 0; d < 128; ++d) s = fmaf(Wo[cout * 128 + d], Wf[d * 512 + k], s);
    const int dir = k >> 7, dm = k & 127;
    Mrow[(dir * 64 + cout) * 128 + dm] = f2bf(s);
  } else if (wg == 128) {
    if (t < 128) A_t[t] = tanhf(A_param[t]);
    if (t < 64) {
      float s = bo[t];
      for (int d = 0; d < 128; ++d) s = fmaf(Wo[t * 128 + d], bf_[d], s);
      beff[t] = s;
    }
  } else {
    // Wi[128 d][64 c] f32 -> bf16, same layout
#pragma unroll
    for (int k = 0; k < 32; ++k) {
      const int i = t + k * 256;
      Wi_bf[i] = f2bf(Wi[i]);
    }
  }
}

extern __shared__ char smem[];

// ---- Chunked scan: local pass (pk math). buf = [128 pos][128B] swz; dp = u32 pair column.
template <bool REV>
DEVINL void scan_local(char* buf, int dp, int chunk, f32x2 A2, f32x2 B2) {
  f32x2 h = { 0.f, 0.f };
  const u32 cb = (u32)(dp * 4);
  const int s = chunk * 32;
  u32 nx[8];
#pragma unroll
  for (int j = 0; j < 8; ++j) {
    const int i = REV ? (127 - (s + j)) : (s + j);
    nx[j] = *(const u32*)(buf + i * 128 + (cb ^ ((u32)((i & 7) << 4))));
  }
  for (int ib = 0; ib < 32; ib += 8) {
    u32 cur[8];
#pragma unroll
    for (int j = 0; j < 8; ++j) cur[j] = nx[j];
    if (ib + 8 < 32) {
#pragma unroll
      for (int j = 0; j < 8; ++j) {
        const int i2 = s + ib + 8 + j;
        const int i = REV ? (127 - i2) : i2;
        nx[j] = *(const u32*)(buf + i * 128 + (cb ^ ((u32)((i & 7) << 4))));
      }
    }
#pragma unroll
    for (int j = 0; j < 8; ++j) {
      const int i2 = s + ib + j;
      const int i = REV ? (127 - i2) : i2;
      const f32x2 xv = { bf2f_lo(cur[j]), bf2f_hi(cur[j]) };
      h = A2 * h + B2 * xv;                       // v_pk_fma_f32 path
      *(u32*)(buf + i * 128 + (cb ^ ((u32)((i & 7) << 4)))) = pack2(h.x, h.y);
    }
  }
}

// ---- Chunked scan: carry correction (pk math). h_i = l_i + A^{j+1} * C.
template <bool REV>
DEVINL void scan_fix(char* buf, int dp, int chunk, f32x2 A2) {
  if (chunk == 0) return;
  f32x2 q = A2;
#pragma unroll
  for (int k = 0; k < 5; ++k) q *= q;            // A^32
  const u32 cb = (u32)(dp * 4);
  f32x2 C = { 0.f, 0.f };
  for (int k = 0; k < chunk; ++k) {
    const int i2 = k * 32 + 31;
    const int i = REV ? (127 - i2) : i2;
    const u32 v = *(const u32*)(buf + i * 128 + (cb ^ ((u32)((i & 7) << 4))));
    const f32x2 xv = { bf2f_lo(v), bf2f_hi(v) };
    C = C * q + xv;
  }
  f32x2 p = A2;
  const int s = chunk * 32;
  u32 nx[8];
#pragma unroll
  for (int j = 0; j < 8; ++j) {
    const int i = REV ? (127 - (s + j)) : (s + j);
    nx[j] = *(const u32*)(buf + i * 128 + (cb ^ ((u32)((i & 7) << 4))));
  }
  for (int ib = 0; ib < 32; ib += 8) {
    u32 cur[8];
#pragma unroll
    for (int j = 0; j < 8; ++j) cur[j] = nx[j];
    if (ib + 8 < 32) {
#pragma unroll
      for (int j = 0; j < 8; ++j) {
        const int i2 = s + ib + 8 + j;
        const int i = REV ? (127 - i2) : i2;
        nx[j] = *(const u32*)(buf + i * 128 + (cb ^ ((u32)((i & 7) << 4))));
      }
    }
#pragma unroll
    for (int j = 0; j < 8; ++j) {
      const int i2 = s + ib + j;
      const int i = REV ? (127 - i2) : i2;
      const f32x2 xv = { bf2f_lo(cur[j]), bf2f_hi(cur[j]) };
      const f32x2 hv = p * C + xv;
      *(u32*)(buf + i * 128 + (cb ^ ((u32)((i & 7) << 4)))) = pack2(hv.x, hv.y);
      p *= A2;
    }
  }
}

// Both scans for a block: dir0 = fwd on bufA, dir1 = rev on bufB; 4 chunks each.
DEVINL void run_scans(char* bufA, char* bufB, int t, int e,
                      const float* __restrict__ A_t, const float* __restrict__ Bp) {
  const int dp = t & 31, chunk = (t >> 5) & 3, dir = t >> 7;
  const int dgp = e * 64 + dp * 2;
  const f32x2 a = *(const f32x2*)(A_t + dgp);
  const f32x2 bb = *(const f32x2*)(Bp + dgp);
  char* sb = dir ? bufB : bufA;
  if (dir == 0) scan_local<false>(sb, dp, chunk, a, bb);
  else          scan_local<true >(sb, dp, chunk, a, bb);
  __syncthreads();
  if (dir == 0) scan_fix<false>(sb, dp, chunk, a);
  else          scan_fix<true >(sb, dp, chunk, a);
}

// acc2 += h @ M[dir]^T in D[pos][c] orientation (h as A-operand, M as B-operand).
DEVINL void combine64(const char* buf, const u16* __restrict__ Mrow, int dir, int e,
                      int lane, int wv, f32x4v (&acc2)[4][2]) {
  const int l15 = lane & 15, kg = lane >> 4;
#pragma unroll
  for (int ks = 0; ks < 2; ++ks) {
    bf16x8 afr[4], bfr[2];
#pragma unroll
    for (int ct = 0; ct < 4; ++ct)
      afr[ct] = *(const bf16x8*)(Mrow + ((size_t)dir * 64 + ct * 16 + l15) * 128 + e * 64 + ks * 32 + kg * 8);
#pragma unroll
    for (int pt = 0; pt < 2; ++pt) {
      const int row = wv * 32 + pt * 16 + l15;
      bfr[pt] = *(const bf16x8*)(buf + row * 128 + ((u32)(ks * 64 + kg * 16) ^ ((u32)((row & 7) << 4))));
    }
    // swapped operands: D[m=pos][n=c]
#pragma unroll
    for (int ct = 0; ct < 4; ++ct)
#pragma unroll
      for (int pt = 0; pt < 2; ++pt)
        acc2[ct][pt] = __builtin_amdgcn_mfma_f32_16x16x32_bf16(bfr[pt], afr[ct], acc2[ct][pt], 0, 0, 0);
  }
}

// Store combine acc into smem as f32 [64 c][512B swz rows]; thread's f32x4 is pos-contiguous.
DEVINL void acc_to_outs(const f32x4v (&acc2)[4][2], int lane, int wv, char* buf) {
  const int l15 = lane & 15, kg = lane >> 4;
#pragma unroll
  for (int ct = 0; ct < 4; ++ct)
#pragma unroll
    for (int pt = 0; pt < 2; ++pt) {
      const int c = ct * 16 + l15;
      const int pos = wv * 32 + pt * 16 + kg * 4;
      *(f32x4v*)(buf + c * 512 + ((u32)(pos * 4) ^ ((u32)((c & 7) << 4)))) = acc2[ct][pt];
    }
}

// Epilogue: OutS -> partial [64 c][128 pos] bf16 stream (16 KB).
DEVINL void outs_to_global(const char* buf, u16* __restrict__ og, int t) {
#pragma unroll
  for (int j = 0; j < 16; ++j) {
    const int i = t + j * 256;
    const int c = i >> 6, p2 = (i & 63) * 2;
    const f32x2 v = *(const f32x2*)(buf + c * 512 + ((u32)(p2 * 4) ^ ((u32)((c & 7) << 4))));
    *(u32*)(og + c * 128 + p2) = pack2(v.x, v.y);
  }
}

// ---------------- K_A: x-GEMM (64 d half) + horizontal scans + combine ----------------
// bid = ((b*128)+h)*2+e. Writes x2[bid][w][64] and Shp[bid][c][w] (both 16 KB streams).
__global__ __launch_bounds__(256, 5) void k_A(
    const float* __restrict__ F_in, const float* __restrict__ prior,
    const u16* __restrict__ Wi_bf, const float* __restrict__ bi,
    const float* __restrict__ Bp, const float* __restrict__ alpha_p,
    const float* __restrict__ A_t, const u16* __restrict__ Mrow,
    u16* __restrict__ x2, u16* __restrict__ Shp) {
  char* bufA = smem;            // 16 KB [128][128B] swz: FT -> x -> h_lr
  char* bufB = smem + 16384;    // 16 KB: x copy -> h_rl

  const int t = threadIdx.x;
  const int lane = t & 63, wv = t >> 6, l15 = lane & 15, kg = lane >> 4;
  const int bid = blockIdx.x;
  const int b = bid >> 8, h = (bid >> 1) & 127, e = bid & 1;

  // ---- P1: stage Fmod^T bf16 into bufA: row w = 64 c (128B), swz ----
  {
    const int w = t & 127, ch = t >> 7;
    const float alpha = alpha_p[0];
    const float pv = prior[(b * 128 + h) * 128 + w];
    const float* Fb = F_in + ((size_t)b * 64 + ch * 32) * 16384 + h * 128 + w;
    const u32 sw = (u32)((w & 7) << 4);
    char* rowp = bufA + w * 128;
#pragma unroll
    for (int q = 0; q < 4; ++q) {
      float fv[8];
#pragma unroll
      for (int j = 0; j < 8; ++j) fv[j] = fmaf(alpha, pv, Fb[(q * 8 + j) * 16384]);
      uint4 pk;
      pk.x = pack2(fv[0], fv[1]); pk.y = pack2(fv[2], fv[3]);
      pk.z = pack2(fv[4], fv[5]); pk.w = pack2(fv[6], fv[7]);
      *(uint4*)(rowp + ((u32)(ch * 64 + q * 16) ^ sw)) = pk;
    }
  }
  __syncthreads();

  // ---- P2: Fmod B-frags (n=w) into regs before bufA is overwritten ----
  bf16x8 bF[2][2];   // [wj][ks]
#pragma unroll
  for (int wj = 0; wj < 2; ++wj)
#pragma unroll
    for (int ks = 0; ks < 2; ++ks) {
      const int row = wv * 32 + wj * 16 + l15;
      bF[wj][ks] = *(const bf16x8*)(bufA + row * 128 + ((u32)(ks * 64 + kg * 16) ^ ((u32)((row & 7) << 4))));
    }
  __syncthreads();

  // ---- P3: GEMM D[d][w] (Wi as A-operand); x -> bufA, pos-contiguous 8B stores ----
  {
    f32x4v acc[4][2];   // [dt][wj]
#pragma unroll
    for (int dt = 0; dt < 4; ++dt) {
      const f32x4 bv = *(const f32x4*)(bi + e * 64 + dt * 16 + kg * 4);
      const f32x4v bvv = { bv.x, bv.y, bv.z, bv.w };
#pragma unroll
      for (int wj = 0; wj < 2; ++wj) acc[dt][wj] = bvv;
    }
#pragma unroll
    for (int ks = 0; ks < 2; ++ks)
#pragma unroll
      for (int dt = 0; dt < 4; ++dt) {
        const bf16x8 aWi = *(const bf16x8*)(Wi_bf + (e * 64 + dt * 16 + l15) * 64 + ks * 32 + kg * 8);
        acc[dt][0] = __builtin_amdgcn_mfma_f32_16x16x32_bf16(aWi, bF[0][ks], acc[dt][0], 0, 0, 0);
        acc[dt][1] = __builtin_amdgcn_mfma_f32_16x16x32_bf16(aWi, bF[1][ks], acc[dt][1], 0, 0, 0);
      }
#pragma unroll
    for (int dt = 0; dt < 4; ++dt)
#pragma unroll
      for (int wj = 0; wj < 2; ++wj) {
        const int w = wv * 32 + wj * 16 + l15;
        const int dl = dt * 16 + kg * 4;          // d_local base (8B-aligned*2)
        uint2 pk;
        pk.x = pack2(acc[dt][wj][0], acc[dt][wj][1]);
        pk.y = pack2(acc[dt][wj][2], acc[dt][wj][3]);
        *(uint2*)(bufA + w * 128 + ((u32)(dl * 2) ^ ((u32)((w & 7) << 4)))) = pk;
      }
  }
  __syncthreads();

  // ---- P4: x -> global (16 KB stream) + bufA -> bufB vector copy ----
  {
    u16* xg = x2 + (size_t)bid * 8192;
#pragma unroll
    for (int j = 0; j < 4; ++j) {
      const int idx = t + j * 256;
      const int row = idx >> 3, q = idx & 7;
      const u32 off = (u32)(q * 16) ^ ((u32)((row & 7) << 4));
      const uint4 v = *(const uint4*)(bufA + row * 128 + off);
      *(uint4*)(xg + row * 64 + q * 8) = v;
      *(uint4*)(bufB + row * 128 + off) = v;
    }
  }
  __syncthreads();

  // ---- P5: chunk-parallel scans (all 256 threads) ----
  run_scans(bufA, bufB, t, e, A_t, Bp);
  __syncthreads();

  // ---- P6: combine dir0 (bufA) + dir1 (bufB) ----
  f32x4v acc2[4][2];
#pragma unroll
  for (int i = 0; i < 4; ++i)
#pragma unroll
    for (int j = 0; j < 2; ++j) acc2[i][j] = (f32x4v)0.f;
  combine64(bufA, Mrow, 0, e, lane, wv, acc2);
  combine64(bufB, Mrow, 1, e, lane, wv, acc2);
  __syncthreads();

  // ---- P7: acc -> OutS (32 KB f32 spanning both buffers) ----
  acc_to_outs(acc2, lane, wv, smem);
  __syncthreads();

  // ---- P8: Shp[bid][c][w] (16 KB stream) ----
  outs_to_global(smem, Shp + (size_t)bid * 8192, t);
}

// ---------------- K_B: vertical scans + combine -> Svp[bid][c][h] ----------------
// bid = ((b*128)+w)*2+e.
__global__ __launch_bounds__(256, 5) void k_B(
    const u16* __restrict__ x2, const float* __restrict__ Bp,
    const float* __restrict__ A_t, const u16* __restrict__ Mrow,
    u16* __restrict__ Svp) {
  char* bufA = smem;
  char* bufB = smem + 16384;
  const int t = threadIdx.x;
  const int lane = t & 63, wv = t >> 6;
  const int bid = blockIdx.x;
  const int b = bid >> 8, w = (bid >> 1) & 127, e = bid & 1;

  // ---- P1: stage x rows (h-major) into both buffers; 128B L3-hot segments ----
#pragma unroll
  for (int j = 0; j < 4; ++j) {
    const int idx = t + j * 256;
    const int hh = idx >> 3, q = idx & 7;
    const uint4 v = *(const uint4*)(x2 + ((size_t)((b * 128 + hh) * 2 + e)) * 8192 + w * 64 + q * 8);
    const u32 col = (u32)(q * 16) ^ ((u32)((hh & 7) << 4));
    *(uint4*)(bufA + hh * 128 + col) = v;
    *(uint4*)(bufB + hh * 128 + col) = v;
  }
  __syncthreads();

  // ---- P2: chunk-parallel scans ----
  run_scans(bufA, bufB, t, e, A_t, Bp);
  __syncthreads();

  // ---- P3: combine dir2 (bufA) + dir3 (bufB) ----
  f32x4v acc2[4][2];
#pragma unroll
  for (int i = 0; i < 4; ++i)
#pragma unroll
    for (int j = 0; j < 2; ++j) acc2[i][j] = (f32x4v)0.f;
  combine64(bufA, Mrow, 2, e, lane, wv, acc2);
  combine64(bufB, Mrow, 3, e, lane, wv, acc2);
  __syncthreads();

  // ---- P4: acc -> OutS ----
  acc_to_outs(acc2, lane, wv, smem);
  __syncthreads();

  // ---- P5: Svp[bid][c][h] (16 KB stream) ----
  outs_to_global(smem, Svp + (size_t)bid * 8192, t);
}

// ---------------- F: out = F_mod + gamma*(Sh0+Sh1 + (Sv0+Sv1)^T + beff) ----------------
__global__ __launch_bounds__(256) void k_final(
    const float* __restrict__ F_in, const float* __restrict__ prior,
    const float* __restrict__ alpha_p, const float* __restrict__ gamma_p,
    const float* __restrict__ beff, const u16* __restrict__ Svp,
    const u16* __restrict__ Shp, float* __restrict__ out) {
  u16* Xu = (u16*)smem;
  const int t = threadIdx.x;
  const int bid = blockIdx.x, b = bid >> 6, c = bid & 63;
  const size_t base = (size_t)bid * 16384;   // (b,c) plane of out/F

  // stage Sv = Svp(e0)+Svp(e1), transposed via LDS: Xu[w][h], stride 132
  for (int i = t; i < 2048; i += 256) {
    const int w = i >> 4, q = i & 15;
    const u16* s0 = Svp + ((size_t)((b * 128 + w) * 2)) * 8192 + c * 128 + q * 8;
    const uint4 a4 = *(const uint4*)(s0);
    const uint4 b4 = *(const uint4*)(s0 + 8192);
    const u16* ap = (const u16*)&a4;
    const u16* bp = (const u16*)&b4;
    u32* dst = (u32*)(Xu + w * 132 + q * 8);
#pragma unroll
    for (int k = 0; k < 4; ++k) {
      const float lo = bf2f(ap[k * 2]) + bf2f(bp[k * 2]);
      const float hi = bf2f(ap[k * 2 + 1]) + bf2f(bp[k * 2 + 1]);
      dst[k] = pack2(lo, hi);
    }
  }
  __syncthreads();
  const float alpha = alpha_p[0], gamma = gamma_p[0];
  const float be = beff[c];
  for (int i = t; i < 2048; i += 256) {
    const int hh = i >> 4, w8 = (i & 15) * 8;
    const size_t off = base + hh * 128 + w8;
    const u16* sh0 = Shp + ((size_t)((b * 128 + hh) * 2)) * 8192 + c * 128 + w8;
    const uint4 g0 = *(const uint4*)(sh0);
    const uint4 g1 = *(const uint4*)(sh0 + 8192);
    const u16* p0 = (const u16*)&g0;
    const u16* p1 = (const u16*)&g1;
    const float* Fp = F_in + off;
    float* Op = out + off;
    const float* Pp = prior + (b * 128 + hh) * 128 + w8;
#pragma unroll
    for (int q = 0; q < 8; ++q) {
      const float sv = bf2f(Xu[(w8 + q) * 132 + hh]);
      Op[q] = Fp[q] + alpha * Pp[q] + gamma * (bf2f(p0[q]) + bf2f(p1[q]) + sv + be);
    }
  }
}

extern "C" void kernel_launch(void* const* d_in, const int* in_sizes, int n_in,
                              void* d_out, int out_size, void* d_ws, size_t ws_size,
                              hipStream_t stream) {
  const float* F_in   = (const float*)d_in[0];
  const float* prior  = (const float*)d_in[1];
  const float* Wi     = (const float*)d_in[2];
  const float* bi     = (const float*)d_in[3];
  const float* A_par  = (const float*)d_in[4];
  const float* B_par  = (const float*)d_in[5];
  const float* alpha  = (const float*)d_in[6];
  const float* gamma  = (const float*)d_in[7];
  const float* Wf     = (const float*)d_in[8];
  const float* bf_    = (const float*)d_in[9];
  const float* Wo     = (const float*)d_in[10];
  const float* bo     = (const float*)d_in[11];
  float* out = (float*)d_out;

  char* ws = (char*)d_ws;
  float* A_t   = (float*)ws;                        // 512 B
  float* beff  = (float*)(ws + 512);                // 256 B
  u16*   Mrow  = (u16*)(ws + 1024);                 // 64 KB: [4][64][128] bf16
  u16*   Wi_bf = (u16*)(ws + 66560);                // 16 KB: [128][64] bf16
  u16*   x2    = (u16*)(ws + 82944);                // 33.5 MB: [2048][128 w][64 d]
  u16*   Shp   = (u16*)(ws + 82944 + 33554432);     // 33.5 MB: [2048][64 c][128 w]
  u16*   Svp   = (u16*)(ws + 82944 + 67108864);     // 33.5 MB: [2048][64 c][128 h]

  hipFuncSetAttribute((const void*)k_A, hipFuncAttributeMaxDynamicSharedMemorySize, SCAN_LDS);
  hipFuncSetAttribute((const void*)k_B, hipFuncAttributeMaxDynamicSharedMemorySize, SCAN_LDS);

  k_pre  <<<130, 256, 0, stream>>>(Wf, Wo, bf_, bo, A_par, Wi, A_t, beff, Mrow, Wi_bf);
  k_A    <<<2048, 256, SCAN_LDS, stream>>>(F_in, prior, Wi_bf, bi, B_par, alpha, A_t, Mrow, x2, Shp);
  k_B    <<<2048, 256, SCAN_LDS, stream>>>(x2, B_par, A_t, Mrow, Svp);
  k_final<<<512, 256, LDS_X, stream>>>(F_in, prior, alpha, gamma, beff, Svp, Shp, out);
}